// Round 5
// baseline (1958.956 us; speedup 1.0000x reference)
//
#include <hip/hip_runtime.h>
#include <math.h>

// ---------------------------------------------------------------------------
// DiffPool GNN (N=8192, E=262144, F=H=128, C1=1024, C2=128, NC=16).
// R5: L2-segmented SpMM (8 x 128-col passes); split-K partial-store + fused
// reduce/sumsq (no atomics, no zero-memsets); algebraic l2; fused colsums.
// ---------------------------------------------------------------------------

#define N_NODES 8192
#define N_EDGES 262144

typedef __attribute__((ext_vector_type(8))) short short8;
typedef __attribute__((ext_vector_type(4))) float floatx4;

// ---------------- workspace layout (float-slot offsets, 16-aligned) ----------------
#define OFF_DEG     0           // 8192  (zeroed)
#define OFF_CNTC    8192        // 8192  (zeroed)
#define OFF_CNTR    16384       // 8192  (zeroed)
#define OFF_SCAL    24576       // 16    (zeroed) [0]=e1 [1]=cross [2]=g2 [3]=sumA2
                                //                [4]=ss_adj1 [5]=e2 [6]=cross2 [7]=g2b
#define ZERO_FLOATS 24592
#define OFF_COLPTR  24592       // 8193
#define OFF_ROWPTR  32785       // 8193
#define OFF_CURC    40978       // 8192 (later: colsum partials, 16x1024 spans CURC+CURR)
#define OFF_CURR    49170       // 8192
#define OFF_COLR    57362       // E (int)
#define OFF_COLN    319506      // E
#define OFF_ROWC    581650      // E (int)
#define OFF_ROWW    843794      // E
#define OFF_DINV    1105938     // 8192
#define OFF_X0      1114144     // 8192*128 fp32 (x0_, live to the end)
#define OFF_H0      2162720     // h0b bf16 [8192][128]
// Region A:
#define OFF_S       3211296     // Sb bf16 [8192][1024]; then TT bf16; then an1 fp32
#define OFF_TT      OFF_S
#define OFF_AN1     OFF_S
#define OFF_X0T     7405600     // bf16 [128][8192]
#define OFF_X0B     7929888     // bf16 [8192][128]
#define A2          8454176
#define OFF_X1      (A2+0)            // 1024*128
#define OFF_HA      (A2+131072)       // 1024*128 (later: y 1024*16)
#define OFF_X1_     (A2+262144)
#define OFF_HB      (A2+393216)
#define OFF_S2      (A2+524288)
#define OFF_S2S     (A2+655360)
#define OFF_U       (A2+786432)
#define OFF_X2      (A2+917504)       // 128*128
#define OFF_ADJ2    (A2+933888)
#define OFF_HC      (A2+950272)
#define OFF_X2_     (A2+966656)
#define OFF_AN2     (A2+983040)
#define OFF_Z2      (A2+999424)       // 128*128
#define OFF_HCAT    (A2+1130496)      // 1024*128
#define OFF_X1O     (A2+1261568)      // 1024*128
#define OFF_P16     (A2+1392640)      // 8192*16
#define OFF_H16     (A2+1523712)
#define OFF_DI1     (A2+1654784)      // 1024
#define OFF_DF1     (A2+1655808)
#define OFF_DI2     (A2+1656832)      // 128
#define OFF_DF2     (A2+1656960)
// Region B:
#define OFF_ST      10111264          // S_T bf16 [1024][8192]
#define OFF_TBF     14305568          // t bf16 [8192][1024]; WP1T aliases start; later PADJ
#define OFF_WP1T    OFF_TBF
#define OFF_PADJ    OFF_TBF           // fp32 [4][1024][1024] (TBF dead by then)
// Extension (ws is ~1 GiB; we use 94.6 MB total):
#define OFF_PG      18499872          // fp32 [4][1024][1024]
#define OFF_PX1     22694176          // fp32 [16][1024][128]
// total: 24,791,328 float-slots = 94.6 MiB

// ------------------- output layout (floats) -------------------
#define OUT_PRED 0          // 8192*16
#define OUT_S1   131072     // 8192*1024
#define OUT_LOSS 8519680    // 1
#define OUT_ADJ1 8519681    // 1024*1024

__device__ __forceinline__ unsigned short f2bf(float f) {
    union { float f; unsigned u; } v; v.f = f;
    unsigned r = (v.u + 0x7FFF + ((v.u >> 16) & 1)) >> 16;
    return (unsigned short)r;
}
__device__ __forceinline__ float bf2f(unsigned short b) {
    union { unsigned u; float f; } v; v.u = (unsigned)b << 16; return v.f;
}

// =========================== graph-structure kernels ===========================

__global__ void k_hist(const int* __restrict__ row, const int* __restrict__ col,
                       const float* __restrict__ ew, int E,
                       float* deg, int* cntc, int* cntr, float* sumA2) {
    __shared__ float red[256];
    int e = blockIdx.x * 256 + threadIdx.x;
    float w2 = 0.f;
    if (e < E) {
        int r = row[e], c = col[e];
        float w = ew[e];
        atomicAdd(&deg[c], w);
        atomicAdd(&cntc[c], 1);
        atomicAdd(&cntr[r], 1);
        w2 = w * w;
    }
    red[threadIdx.x] = w2; __syncthreads();
    for (int s = 128; s > 0; s >>= 1) { if (threadIdx.x < s) red[threadIdx.x] += red[threadIdx.x + s]; __syncthreads(); }
    if (threadIdx.x == 0) atomicAdd(sumA2, red[0]);
}

__global__ void k_dinv(const float* deg, float* dinv, int n) {
    int i = blockIdx.x * 256 + threadIdx.x;
    if (i < n) {
        float d = deg[i] + 1.0f;
        dinv[i] = (d > 0.f) ? 1.0f / sqrtf(d) : 0.f;
    }
}

__global__ __launch_bounds__(1024) void k_scan(const int* cntc, const int* cntr,
        int* colptr, int* rowptr, int* curc, int* curr, int n, int E) {
    __shared__ int part[1024];
    int tid = threadIdx.x;
    const int per = 8;
    for (int pass = 0; pass < 2; ++pass) {
        const int* cnt = pass ? cntr : cntc;
        int* ptr = pass ? rowptr : colptr;
        int* cur = pass ? curr : curc;
        int st = tid * per;
        int loc[per]; int s = 0;
        for (int i = 0; i < per; ++i) { loc[i] = s; s += cnt[st + i]; }
        part[tid] = s; __syncthreads();
        for (int off = 1; off < 1024; off <<= 1) {
            int v = part[tid];
            int add = (tid >= off) ? part[tid - off] : 0;
            __syncthreads();
            part[tid] = v + add;
            __syncthreads();
        }
        int pre = (tid == 0) ? 0 : part[tid - 1];
        for (int i = 0; i < per; ++i) { int v = pre + loc[i]; ptr[st + i] = v; cur[st + i] = v; }
        if (tid == 0) ptr[n] = E;
        __syncthreads();
    }
}

__global__ void k_scatter(const int* __restrict__ row, const int* __restrict__ col,
                          const float* __restrict__ ew, int E, const float* __restrict__ dinv,
                          int* curc, int* curr, int* colr, float* coln, int* rowc, float* roww) {
    int e = blockIdx.x * 256 + threadIdx.x;
    if (e >= E) return;
    int r = row[e], c = col[e];
    float w = ew[e];
    float nrm = dinv[r] * w * dinv[c];
    int p = atomicAdd(&curc[c], 1);
    colr[p] = r; coln[p] = nrm;
    int q = atomicAdd(&curr[r], 1);
    rowc[q] = c; roww[q] = w;
}

// =========================== fp32 GEMMs ===========================

// 64x64 tile, bf16 output (h0b = x0 @ W0_in)
__global__ __launch_bounds__(256) void gemm_ab_b16(const float* __restrict__ A, const float* __restrict__ B,
        unsigned short* __restrict__ C, int M, int N, int K) {
    __shared__ float As[16][68];
    __shared__ float Bs[16][68];
    int tid = threadIdx.x, tx = tid & 15, ty = tid >> 4;
    int m0 = blockIdx.y * 64, n0 = blockIdx.x * 64;
    float acc[4][4] = {};
    for (int k0 = 0; k0 < K; k0 += 16) {
        for (int l = 0; l < 4; ++l) {
            int idx = tid + 256 * l;
            int mm = idx >> 4, kk = idx & 15;
            As[kk][mm] = A[(size_t)(m0 + mm) * K + k0 + kk];
            int kk2 = idx >> 6, nn = idx & 63;
            Bs[kk2][nn] = B[(size_t)(k0 + kk2) * N + n0 + nn];
        }
        __syncthreads();
        #pragma unroll
        for (int kk = 0; kk < 16; ++kk) {
            float a[4], b[4];
            #pragma unroll
            for (int i = 0; i < 4; ++i) a[i] = As[kk][ty * 4 + i];
            #pragma unroll
            for (int j = 0; j < 4; ++j) b[j] = Bs[kk][tx * 4 + j];
            #pragma unroll
            for (int i = 0; i < 4; ++i)
                #pragma unroll
                for (int j = 0; j < 4; ++j) acc[i][j] += a[i] * b[j];
        }
        __syncthreads();
    }
    for (int i = 0; i < 4; ++i)
        for (int j = 0; j < 4; ++j)
            C[(size_t)(m0 + ty * 4 + i) * N + n0 + tx * 4 + j] = f2bf(acc[i][j]);
}

// 32x32 tile, C = A@B (+bias/relu/accum)
__global__ __launch_bounds__(256) void gemm_ab32(const float* __restrict__ A, const float* __restrict__ B,
        float* __restrict__ C, int M, int N, int K,
        const float* __restrict__ bias, int relu, int accum) {
    __shared__ float As[32][33];
    __shared__ float Bs[32][33];
    int tid = threadIdx.x, tx = tid & 15, ty = tid >> 4;
    int m0 = blockIdx.y * 32, n0 = blockIdx.x * 32;
    float acc[2][2] = {};
    for (int k0 = 0; k0 < K; k0 += 32) {
        #pragma unroll
        for (int l = 0; l < 4; ++l) {
            int idx = tid + 256 * l;
            int r = idx >> 5, c = idx & 31;
            As[r][c] = A[(size_t)(m0 + r) * K + k0 + c];
            Bs[r][c] = B[(size_t)(k0 + r) * N + n0 + c];
        }
        __syncthreads();
        #pragma unroll
        for (int kk = 0; kk < 32; ++kk) {
            float a0 = As[ty * 2][kk], a1 = As[ty * 2 + 1][kk];
            float b0 = Bs[kk][tx * 2], b1 = Bs[kk][tx * 2 + 1];
            acc[0][0] += a0 * b0; acc[0][1] += a0 * b1;
            acc[1][0] += a1 * b0; acc[1][1] += a1 * b1;
        }
        __syncthreads();
    }
    #pragma unroll
    for (int i = 0; i < 2; ++i)
        #pragma unroll
        for (int j = 0; j < 2; ++j) {
            int m = m0 + ty * 2 + i, n = n0 + tx * 2 + j;
            float v = acc[i][j];
            if (accum) v += C[(size_t)m * N + n];
            if (bias) v += bias[n];
            if (relu) v = fmaxf(v, 0.f);
            C[(size_t)m * N + n] = v;
        }
}

// 32x32 tile, C = A^T@B with A[K][M], B[K][N]; optional sumsq-only mode.
__global__ __launch_bounds__(256) void gemm_atb32(const float* __restrict__ A, const float* __restrict__ B,
        float* __restrict__ C, int M, int N, int K,
        const float* __restrict__ bias, int relu, float* sumsq_acc) {
    __shared__ float As[32][33];
    __shared__ float Bs[32][33];
    __shared__ float red[256];
    int tid = threadIdx.x, tx = tid & 15, ty = tid >> 4;
    int m0 = blockIdx.y * 32, n0 = blockIdx.x * 32;
    float acc[2][2] = {};
    for (int k0 = 0; k0 < K; k0 += 32) {
        #pragma unroll
        for (int l = 0; l < 4; ++l) {
            int idx = tid + 256 * l;
            int r = idx >> 5, c = idx & 31;
            As[c][r] = A[(size_t)(k0 + r) * M + m0 + c];
            Bs[r][c] = B[(size_t)(k0 + r) * N + n0 + c];
        }
        __syncthreads();
        #pragma unroll
        for (int kk = 0; kk < 32; ++kk) {
            float a0 = As[ty * 2][kk], a1 = As[ty * 2 + 1][kk];
            float b0 = Bs[kk][tx * 2], b1 = Bs[kk][tx * 2 + 1];
            acc[0][0] += a0 * b0; acc[0][1] += a0 * b1;
            acc[1][0] += a1 * b0; acc[1][1] += a1 * b1;
        }
        __syncthreads();
    }
    if (sumsq_acc) {
        float ss = acc[0][0] * acc[0][0] + acc[0][1] * acc[0][1]
                 + acc[1][0] * acc[1][0] + acc[1][1] * acc[1][1];
        red[tid] = ss; __syncthreads();
        for (int s = 128; s > 0; s >>= 1) { if (tid < s) red[tid] += red[tid + s]; __syncthreads(); }
        if (tid == 0) atomicAdd(sumsq_acc, red[0]);
        return;
    }
    #pragma unroll
    for (int i = 0; i < 2; ++i)
        #pragma unroll
        for (int j = 0; j < 2; ++j) {
            int m = m0 + ty * 2 + i, n = n0 + tx * 2 + j;
            float v = acc[i][j];
            if (bias) v += bias[n];
            if (relu) v = fmaxf(v, 0.f);
            C[(size_t)m * N + n] = v;
        }
}

// C[M][16] (+)= A[M][K] @ B[K][16]
__global__ __launch_bounds__(256) void k_gemm_n16(const float* __restrict__ A, const float* __restrict__ B,
        float* __restrict__ C, int M, int K, int accum) {
    __shared__ float As[16][64];
    __shared__ float Bs[64][16];
    int tid = threadIdx.x;
    int r = tid >> 4, c = tid & 15;
    int m0 = blockIdx.x * 16;
    float acc = 0.f;
    for (int k0 = 0; k0 < K; k0 += 64) {
        #pragma unroll
        for (int l = 0; l < 4; ++l) {
            int idx = tid + 256 * l;
            int rr = idx >> 6, cc = idx & 63;
            As[rr][cc] = A[(size_t)(m0 + rr) * K + k0 + cc];
            int kk = idx >> 4, c2 = idx & 15;
            Bs[kk][c2] = B[(size_t)(k0 + kk) * 16 + c2];
        }
        __syncthreads();
        #pragma unroll 16
        for (int kk = 0; kk < 64; ++kk) acc += As[r][kk] * Bs[kk][c];
        __syncthreads();
    }
    float* p = &C[(size_t)(m0 + r) * 16 + c];
    if (accum) acc += *p;
    *p = acc;
}

// =========================== bf16 MFMA GEMMs ===========================

// split-K partial-store: P[z][M][N] = partial of A^T B over K-chunk z.
__global__ __launch_bounds__(256) void gemm_tn_bf16_part(
        const unsigned short* __restrict__ A, const unsigned short* __restrict__ B,
        float* __restrict__ P, int M, int N, int K) {
    __shared__ __align__(16) unsigned short As[128 * 64];
    __shared__ __align__(16) unsigned short Bs[128 * 64];
    int tid = threadIdx.x;
    int wave = tid >> 6, lane = tid & 63;
    int wm = wave >> 1, wn = wave & 1;
    int m0 = blockIdx.x * 128, n0 = blockIdx.y * 128;
    int kchunk = K / gridDim.z;
    int k0 = blockIdx.z * kchunk;
    float* Pz = P + (size_t)blockIdx.z * M * N;
    floatx4 acc[4][4] = {};
    int sr = tid >> 3;
    int sc = (tid & 7) * 8;
    int q = lane >> 4, lm = lane & 15;
    for (int kt = 0; kt < kchunk; kt += 64) {
        #pragma unroll
        for (int p = 0; p < 4; ++p) {
            int mrow = sr + p * 32;
            int gk = k0 + kt + sc;
            int scs = sc ^ ((mrow & 7) * 8);
            *(short8*)(&As[mrow * 64 + scs]) = *(const short8*)(&A[(size_t)(m0 + mrow) * K + gk]);
            *(short8*)(&Bs[mrow * 64 + scs]) = *(const short8*)(&B[(size_t)(n0 + mrow) * K + gk]);
        }
        __syncthreads();
        #pragma unroll
        for (int ks = 0; ks < 64; ks += 32) {
            short8 af[4], bf[4];
            int kk = ks + q * 8;
            #pragma unroll
            for (int i = 0; i < 4; ++i) {
                int ml = wm * 64 + i * 16 + lm;
                af[i] = *(const short8*)(&As[ml * 64 + (kk ^ ((ml & 7) * 8))]);
                int nl = wn * 64 + i * 16 + lm;
                bf[i] = *(const short8*)(&Bs[nl * 64 + (kk ^ ((nl & 7) * 8))]);
            }
            #pragma unroll
            for (int i = 0; i < 4; ++i)
                #pragma unroll
                for (int j = 0; j < 4; ++j)
                    acc[i][j] = __builtin_amdgcn_mfma_f32_16x16x32_bf16(af[i], bf[j], acc[i][j], 0, 0, 0);
        }
        __syncthreads();
    }
    for (int i = 0; i < 4; ++i) {
        int rowb = m0 + wm * 64 + i * 16 + q * 4;
        for (int j = 0; j < 4; ++j) {
            int col = n0 + wn * 64 + j * 16 + lm;
            #pragma unroll
            for (int r = 0; r < 4; ++r)
                Pz[(size_t)(rowb + r) * N + col] = acc[i][j][r];
        }
    }
}

// full-K store with bias+relu (s1o)
__global__ __launch_bounds__(256) void gemm_tn_bf16_store(
        const unsigned short* __restrict__ A, const unsigned short* __restrict__ B,
        float* __restrict__ C, int M, int N, int K,
        const float* __restrict__ bias, int relu) {
    __shared__ __align__(16) unsigned short As[128 * 64];
    __shared__ __align__(16) unsigned short Bs[128 * 64];
    int tid = threadIdx.x;
    int wave = tid >> 6, lane = tid & 63;
    int wm = wave >> 1, wn = wave & 1;
    int m0 = blockIdx.x * 128, n0 = blockIdx.y * 128;
    floatx4 acc[4][4] = {};
    int sr = tid >> 3;
    int sc = (tid & 7) * 8;
    int q = lane >> 4, lm = lane & 15;
    for (int kt = 0; kt < K; kt += 64) {
        #pragma unroll
        for (int p = 0; p < 4; ++p) {
            int mrow = sr + p * 32;
            int gk = kt + sc;
            int scs = sc ^ ((mrow & 7) * 8);
            *(short8*)(&As[mrow * 64 + scs]) = *(const short8*)(&A[(size_t)(m0 + mrow) * K + gk]);
            *(short8*)(&Bs[mrow * 64 + scs]) = *(const short8*)(&B[(size_t)(n0 + mrow) * K + gk]);
        }
        __syncthreads();
        #pragma unroll
        for (int ks = 0; ks < 64; ks += 32) {
            short8 af[4], bf[4];
            int kk = ks + q * 8;
            #pragma unroll
            for (int i = 0; i < 4; ++i) {
                int ml = wm * 64 + i * 16 + lm;
                af[i] = *(const short8*)(&As[ml * 64 + (kk ^ ((ml & 7) * 8))]);
                int nl = wn * 64 + i * 16 + lm;
                bf[i] = *(const short8*)(&Bs[nl * 64 + (kk ^ ((nl & 7) * 8))]);
            }
            #pragma unroll
            for (int i = 0; i < 4; ++i)
                #pragma unroll
                for (int j = 0; j < 4; ++j)
                    acc[i][j] = __builtin_amdgcn_mfma_f32_16x16x32_bf16(af[i], bf[j], acc[i][j], 0, 0, 0);
        }
        __syncthreads();
    }
    for (int i = 0; i < 4; ++i) {
        int rowb = m0 + wm * 64 + i * 16 + q * 4;
        for (int j = 0; j < 4; ++j) {
            int col = n0 + wn * 64 + j * 16 + lm;
            float bv = bias ? bias[col] : 0.f;
            #pragma unroll
            for (int r = 0; r < 4; ++r) {
                float v = acc[i][j][r] + bv;
                if (relu) v = fmaxf(v, 0.f);
                C[(size_t)(rowb + r) * N + col] = v;
            }
        }
    }
}

// reduce nsplit partials of length n (float4-vectorized); optional store + sumsq.
__global__ __launch_bounds__(256) void k_reduce4(const float* __restrict__ P,
        float* __restrict__ C, int n, int nsplit, float* ss_acc) {
    __shared__ float red[256];
    float ss = 0.f;
    for (int i4 = (blockIdx.x * 256 + threadIdx.x) * 4; i4 < n; i4 += gridDim.x * 256 * 4) {
        float4 v = *(const float4*)(P + i4);
        for (int s = 1; s < nsplit; ++s) {
            float4 w = *(const float4*)(P + (size_t)s * n + i4);
            v.x += w.x; v.y += w.y; v.z += w.z; v.w += w.w;
        }
        if (C) *(float4*)(C + i4) = v;
        ss += v.x * v.x + v.y * v.y + v.z * v.z + v.w * v.w;
    }
    if (!ss_acc) return;
    red[threadIdx.x] = ss; __syncthreads();
    for (int s = 128; s > 0; s >>= 1) { if (threadIdx.x < s) red[threadIdx.x] += red[threadIdx.x + s]; __syncthreads(); }
    if (threadIdx.x == 0) atomicAdd(ss_acc, red[0]);
}

// =========================== transposes ===========================

__global__ __launch_bounds__(256) void k_transpose_f2b(
        const float* __restrict__ in, unsigned short* __restrict__ outb,
        int R, int C, const float* __restrict__ rowscale) {
    __shared__ float tile[64][65];
    int rb = blockIdx.y * 64, cb = blockIdx.x * 64;
    int t = threadIdx.x;
    int lr = t >> 4, lc4 = (t & 15) * 4;
    #pragma unroll
    for (int p = 0; p < 4; ++p) {
        int r = rb + lr + p * 16;
        float4 v = *(const float4*)(in + (size_t)r * C + cb + lc4);
        float s = rowscale ? rowscale[r] : 1.0f;
        tile[lr + p * 16][lc4 + 0] = v.x * s;
        tile[lr + p * 16][lc4 + 1] = v.y * s;
        tile[lr + p * 16][lc4 + 2] = v.z * s;
        tile[lr + p * 16][lc4 + 3] = v.w * s;
    }
    __syncthreads();
    int cc0 = t >> 5, rr = (t & 31) * 2;
    #pragma unroll
    for (int p = 0; p < 8; ++p) {
        int cc = cc0 + p * 8;
        unsigned a = f2bf(tile[rr][cc]);
        unsigned b = f2bf(tile[rr + 1][cc]);
        *(unsigned*)(outb + (size_t)(cb + cc) * R + rb + rr) = a | (b << 16);
    }
}

__global__ __launch_bounds__(256) void k_transpose_b2b(
        const unsigned short* __restrict__ in, unsigned short* __restrict__ out, int R, int C) {
    __shared__ __align__(16) unsigned short tile[64][72];
    int rb = blockIdx.y * 64, cb = blockIdx.x * 64;
    int t = threadIdx.x;
    int lr = t >> 3, lc = (t & 7) * 8;
    #pragma unroll
    for (int p = 0; p < 2; ++p) {
        int r = lr + p * 32;
        *(short8*)(&tile[r][lc]) = *(const short8*)(&in[(size_t)(rb + r) * C + cb + lc]);
    }
    __syncthreads();
    int cc0 = t >> 4, rr = (t & 15) * 4;
    #pragma unroll
    for (int p = 0; p < 4; ++p) {
        int cc = cc0 + p * 16;
        unsigned long long v = (unsigned long long)tile[rr][cc]
                             | ((unsigned long long)tile[rr + 1][cc] << 16)
                             | ((unsigned long long)tile[rr + 2][cc] << 32)
                             | ((unsigned long long)tile[rr + 3][cc] << 48);
        *(unsigned long long*)(&out[(size_t)(cb + cc) * R + rb + rr]) = v;
    }
}

// =========================== aggregation / misc ===========================

__global__ __launch_bounds__(64) void k_agg_b16(const unsigned short* __restrict__ h,
        float* __restrict__ out, unsigned short* __restrict__ outb,
        const int* __restrict__ cptr, const int* __restrict__ colr,
        const float* __restrict__ coln, const float* __restrict__ dinv,
        const float* __restrict__ bias, int relu) {
    int c = blockIdx.x, t = threadIdx.x;
    int f0 = t * 2;
    float d = dinv[c], dd = d * d;
    unsigned u = *(const unsigned*)(h + (size_t)c * 128 + f0);
    float a0 = dd * bf2f((unsigned short)(u & 0xffff));
    float a1 = dd * bf2f((unsigned short)(u >> 16));
    int e0 = cptr[c], e1 = cptr[c + 1];
    for (int e = e0; e < e1; ++e) {
        float w = coln[e];
        unsigned v = *(const unsigned*)(h + (size_t)colr[e] * 128 + f0);
        a0 += w * bf2f((unsigned short)(v & 0xffff));
        a1 += w * bf2f((unsigned short)(v >> 16));
    }
    if (bias) { a0 += bias[f0]; a1 += bias[f0 + 1]; }
    if (relu) { a0 = fmaxf(a0, 0.f); a1 = fmaxf(a1, 0.f); }
    if (out) { out[(size_t)c * 128 + f0] = a0; out[(size_t)c * 128 + f0 + 1] = a1; }
    if (outb) {
        unsigned o = (unsigned)f2bf(a0) | ((unsigned)f2bf(a1) << 16);
        *(unsigned*)(outb + (size_t)c * 128 + f0) = o;
    }
}

__global__ __launch_bounds__(256) void k_agg16(const float* __restrict__ h, float* __restrict__ out,
        const int* __restrict__ cptr, const int* __restrict__ colr,
        const float* __restrict__ coln, const float* __restrict__ dinv,
        const float* __restrict__ bias) {
    int node = blockIdx.x * 16 + (threadIdx.x >> 4);
    int f = threadIdx.x & 15;
    float d = dinv[node];
    float acc = d * d * h[(size_t)node * 16 + f];
    int e0 = cptr[node], e1 = cptr[node + 1];
    for (int e = e0; e < e1; ++e)
        acc += coln[e] * h[(size_t)colr[e] * 16 + f];
    acc += bias[f];
    out[(size_t)node * 16 + f] = fmaxf(acc, 0.f);
}

// single-pass softmax over W=1024, writes bf16 S (masked) + entropy.
__global__ __launch_bounds__(256) void k_softmax1024(const float* __restrict__ x,
        unsigned short* __restrict__ Sb, const float* __restrict__ mask, float* ent_acc) {
    __shared__ float red[256];
    int r = blockIdx.x, tid = threadIdx.x;
    const float* xr = x + (size_t)r * 1024;
    float4 v = *(const float4*)(xr + tid * 4);
    float m = fmaxf(fmaxf(v.x, v.y), fmaxf(v.z, v.w));
    red[tid] = m; __syncthreads();
    for (int s = 128; s > 0; s >>= 1) { if (tid < s) red[tid] = fmaxf(red[tid], red[tid + s]); __syncthreads(); }
    m = red[0]; __syncthreads();
    float e0 = expf(v.x - m), e1 = expf(v.y - m), e2 = expf(v.z - m), e3 = expf(v.w - m);
    red[tid] = e0 + e1 + e2 + e3; __syncthreads();
    for (int s = 128; s > 0; s >>= 1) { if (tid < s) red[tid] += red[tid + s]; __syncthreads(); }
    float inv = 1.0f / red[0]; __syncthreads();
    float mk = mask ? mask[r] : 1.0f;
    float s0 = e0 * inv * mk, s1 = e1 * inv * mk, s2 = e2 * inv * mk, s3 = e3 * inv * mk;
    float ent = -(s0 * logf(s0 + 1e-15f) + s1 * logf(s1 + 1e-15f)
                + s2 * logf(s2 + 1e-15f) + s3 * logf(s3 + 1e-15f));
    ushort4 o;
    o.x = f2bf(s0); o.y = f2bf(s1); o.z = f2bf(s2); o.w = f2bf(s3);
    *(ushort4*)(Sb + (size_t)r * 1024 + tid * 4) = o;
    red[tid] = ent; __syncthreads();
    for (int s = 128; s > 0; s >>= 1) { if (tid < s) red[tid] += red[tid + s]; __syncthreads(); }
    if (tid == 0) atomicAdd(ent_acc, red[0]);
}

__global__ __launch_bounds__(256) void k_softmax_ent(const float* __restrict__ x, float* __restrict__ S,
        int W, const float* __restrict__ mask, float* ent_acc) {
    __shared__ float red[256];
    int row = blockIdx.x, tid = threadIdx.x;
    const float* xr = x + (size_t)row * W;
    float m = -3.0e38f;
    for (int q = tid; q < W; q += 256) m = fmaxf(m, xr[q]);
    red[tid] = m; __syncthreads();
    for (int s = 128; s > 0; s >>= 1) { if (tid < s) red[tid] = fmaxf(red[tid], red[tid + s]); __syncthreads(); }
    m = red[0]; __syncthreads();
    float sum = 0.f;
    for (int q = tid; q < W; q += 256) sum += expf(xr[q] - m);
    red[tid] = sum; __syncthreads();
    for (int s = 128; s > 0; s >>= 1) { if (tid < s) red[tid] += red[tid + s]; __syncthreads(); }
    float inv = 1.0f / red[0]; __syncthreads();
    float mk = mask ? mask[row] : 1.0f;
    float* Sr = S + (size_t)row * W;
    float ent = 0.f;
    for (int q = tid; q < W; q += 256) {
        float v = expf(xr[q] - m) * inv * mk;
        Sr[q] = v;
        ent -= v * logf(v + 1e-15f);
    }
    red[tid] = ent; __syncthreads();
    for (int s = 128; s > 0; s >>= 1) { if (tid < s) red[tid] += red[tid + s]; __syncthreads(); }
    if (tid == 0) atomicAdd(ent_acc, red[0]);
}

// L2-segmented SpMM: pass p handles S columns [p*128, p*128+128).
// Working set per pass = 8192x128 bf16 = 2 MB -> fits per-XCD L2.
// block = (row r, pass p), 64 threads, 2 cols/thread.
__global__ __launch_bounds__(64) void k_spmm_seg(const unsigned short* __restrict__ Sb,
        const int* __restrict__ rptr, const int* __restrict__ rowc, const float* __restrict__ roww,
        unsigned short* __restrict__ tb, float* cross_acc) {
    int r = blockIdx.x, t = threadIdx.x;
    int j0 = blockIdx.y * 128 + t * 2;
    unsigned su = *(const unsigned*)(Sb + (size_t)r * 1024 + j0);
    float sr0 = bf2f((unsigned short)(su & 0xffff));
    float sr1 = bf2f((unsigned short)(su >> 16));
    float a0 = 0.f, a1 = 0.f, lp = 0.f;
    int e0 = rptr[r], e1 = rptr[r + 1];
    for (int e = e0; e < e1; ++e) {
        int c = rowc[e]; float w = roww[e];
        unsigned v = *(const unsigned*)(Sb + (size_t)c * 1024 + j0);
        float v0 = bf2f((unsigned short)(v & 0xffff));
        float v1 = bf2f((unsigned short)(v >> 16));
        a0 += w * v0; a1 += w * v1;
        lp += w * (sr0 * v0 + sr1 * v1);
    }
    unsigned o = (unsigned)f2bf(a0) | ((unsigned)f2bf(a1) << 16);
    *(unsigned*)(tb + (size_t)r * 1024 + j0) = o;
    #pragma unroll
    for (int off = 32; off > 0; off >>= 1) lp += __shfl_down(lp, off);
    if (t == 0) atomicAdd(cross_acc, lp);
}

// colsum partials: part[by][j] = sum of 64 rows
__global__ void k_colsum_part(const float* __restrict__ adjm, int n, float* part) {
    int j = blockIdx.x * blockDim.x + threadIdx.x;
    if (j >= n) return;
    int r0 = blockIdx.y * 64;
    float s = 0.f;
    for (int r = r0; r < r0 + 64; ++r) s += adjm[(size_t)r * n + j];
    part[(size_t)blockIdx.y * n + j] = s;
}

__global__ void k_dfix_part(const float* __restrict__ adjm, int n, const float* __restrict__ part,
                            int nparts, float* dinvv, float* dfix) {
    int j = blockIdx.x * blockDim.x + threadIdx.x;
    if (j >= n) return;
    float s = 0.f;
    for (int p = 0; p < nparts; ++p) s += part[(size_t)p * n + j];
    float diag = adjm[(size_t)j * n + j];
    float fix = (diag == 0.f) ? 1.0f : 0.f;
    s += fix;
    dfix[j] = fix;
    dinvv[j] = (s > 0.f) ? 1.0f / sqrtf(s) : 0.f;
}

// fused colsum+dfix for n=128
__global__ __launch_bounds__(128) void k_coldfix128(const float* __restrict__ adjm,
        float* dinvv, float* dfix) {
    int j = threadIdx.x;
    float s = 0.f;
    for (int i = 0; i < 128; ++i) s += adjm[(size_t)i * 128 + j];
    float diag = adjm[(size_t)j * 128 + j];
    float fix = (diag == 0.f) ? 1.0f : 0.f;
    s += fix;
    dfix[j] = fix;
    dinvv[j] = (s > 0.f) ? 1.0f / sqrtf(s) : 0.f;
}

__global__ void k_anorm(const float* __restrict__ adjm, int n, const float* __restrict__ dinvv,
                        const float* __restrict__ dfix, float* __restrict__ anorm) {
    int idx = blockIdx.x * 256 + threadIdx.x;
    if (idx >= n * n) return;
    int i = idx / n, j = idx % n;
    float v = adjm[idx] + ((i == j) ? dfix[j] : 0.f);
    anorm[idx] = dinvv[i] * v * dinvv[j];
}

// acc += sum_i a[i]*b[i]
__global__ __launch_bounds__(256) void k_dot(const float* __restrict__ a, const float* __restrict__ b,
        int n, float* acc) {
    __shared__ float red[256];
    float s = 0.f;
    for (int i = blockIdx.x * 256 + threadIdx.x; i < n; i += gridDim.x * 256) s += a[i] * b[i];
    red[threadIdx.x] = s; __syncthreads();
    for (int st = 128; st > 0; st >>= 1) { if (threadIdx.x < st) red[threadIdx.x] += red[threadIdx.x + st]; __syncthreads(); }
    if (threadIdx.x == 0) atomicAdd(acc, red[0]);
}

__global__ void k_logsoftmax(const float* __restrict__ x, float* __restrict__ out, int n) {
    int i = blockIdx.x * 256 + threadIdx.x;
    if (i >= n) return;
    float v[16];
    float m = -3.0e38f;
    #pragma unroll
    for (int j = 0; j < 16; ++j) { v[j] = x[(size_t)i * 16 + j]; m = fmaxf(m, v[j]); }
    float s = 0.f;
    #pragma unroll
    for (int j = 0; j < 16; ++j) s += expf(v[j] - m);
    float ls = m + logf(s);
    #pragma unroll
    for (int j = 0; j < 16; ++j) out[(size_t)i * 16 + j] = v[j] - ls;
}

__global__ void k_finalize(const float* __restrict__ sc, float* loss) {
    if (threadIdx.x == 0 && blockIdx.x == 0) {
        float e1     = sc[0] / 8192.0f;
        float cross  = sc[1];
        float g2     = sc[2];
        float sumA2  = sc[3];
        float ssadj1 = sc[4];
        float e2     = sc[5] / 1024.0f;
        float cross2 = sc[6];
        float g2b    = sc[7];
        float l1 = sqrtf(fmaxf(sumA2 - 2.0f * cross + g2, 0.f)) / 67108864.0f;
        float l2 = sqrtf(fmaxf(ssadj1 - 2.0f * cross2 + g2b, 0.f)) / 1048576.0f;
        *loss = l1 + e1 + l2 + e2;
    }
}

// =========================== launcher ===========================

extern "C" void kernel_launch(void* const* d_in, const int* in_sizes, int n_in,
                              void* d_out, int out_size, void* d_ws, size_t ws_size,
                              hipStream_t stream) {
    const int N = N_NODES, E = N_EDGES;
    const float* x0     = (const float*)d_in[0];
    const int*   eidx   = (const int*)d_in[1];
    const float* ew     = (const float*)d_in[2];
    const float* mask   = (const float*)d_in[4];
    const float* W0_in  = (const float*)d_in[5];
    const float* b0_in  = (const float*)d_in[6];
    const float* Wp1    = (const float*)d_in[7];
    const float* bp1    = (const float*)d_in[8];
    const float* W1_in  = (const float*)d_in[9];
    const float* b1_in  = (const float*)d_in[10];
    const float* Wp2    = (const float*)d_in[11];
    const float* bp2    = (const float*)d_in[12];
    const float* W2_in  = (const float*)d_in[13];
    const float* b2_in  = (const float*)d_in[14];
    const float* W1_out = (const float*)d_in[15];
    const float* b1_out = (const float*)d_in[16];
    const float* W0_out = (const float*)d_in[17];
    const float* b0_out = (const float*)d_in[18];

    float* out   = (float*)d_out;
    float* predo = out + OUT_PRED;
    float* s1o   = out + OUT_S1;
    float* losso = out + OUT_LOSS;
    float* adj1o = out + OUT_ADJ1;

    float* wsf = (float*)d_ws;
    int*   wsi = (int*)d_ws;
    float* deg   = wsf + OFF_DEG;
    int*   cntc  = wsi + OFF_CNTC;
    int*   cntr  = wsi + OFF_CNTR;
    float* scal  = wsf + OFF_SCAL;
    int*   cptr  = wsi + OFF_COLPTR;
    int*   rptr  = wsi + OFF_ROWPTR;
    int*   curc  = wsi + OFF_CURC;
    int*   curr  = wsi + OFF_CURR;
    int*   colr  = wsi + OFF_COLR;
    float* coln  = wsf + OFF_COLN;
    int*   rowc  = wsi + OFF_ROWC;
    float* roww  = wsf + OFF_ROWW;
    float* dinv  = wsf + OFF_DINV;
    float* x0_   = wsf + OFF_X0;
    unsigned short* h0b  = (unsigned short*)(wsf + OFF_H0);
    unsigned short* Sb   = (unsigned short*)(wsf + OFF_S);
    unsigned short* TT   = (unsigned short*)(wsf + OFF_TT);
    unsigned short* ST   = (unsigned short*)(wsf + OFF_ST);
    unsigned short* TBF  = (unsigned short*)(wsf + OFF_TBF);
    unsigned short* WP1T = (unsigned short*)(wsf + OFF_WP1T);
    unsigned short* X0T  = (unsigned short*)(wsf + OFF_X0T);
    unsigned short* x0b  = (unsigned short*)(wsf + OFF_X0B);
    float* an1   = wsf + OFF_AN1;
    float* PADJ  = wsf + OFF_PADJ;
    float* PG    = wsf + OFF_PG;
    float* PX1   = wsf + OFF_PX1;
    float* x1    = wsf + OFF_X1;
    float* hA    = wsf + OFF_HA;
    float* x1_   = wsf + OFF_X1_;
    float* hB    = wsf + OFF_HB;
    float* s2    = wsf + OFF_S2;
    float* S2s   = wsf + OFF_S2S;
    float* u     = wsf + OFF_U;
    float* x2    = wsf + OFF_X2;
    float* adj2  = wsf + OFF_ADJ2;
    float* hC    = wsf + OFF_HC;
    float* x2_   = wsf + OFF_X2_;
    float* an2   = wsf + OFF_AN2;
    float* z2    = wsf + OFF_Z2;
    float* hcat  = wsf + OFF_HCAT;
    float* x1o_  = wsf + OFF_X1O;
    float* p16   = wsf + OFF_P16;
    float* h16   = wsf + OFF_H16;
    float* di1   = wsf + OFF_DI1;
    float* df1   = wsf + OFF_DF1;
    float* di2   = wsf + OFF_DI2;
    float* df2   = wsf + OFF_DF2;
    float* cspart = wsf + OFF_CURC;   // colsum partials (16x1024, spans CURC+CURR)

    const int* row = eidx;
    const int* col = eidx + E;

    hipMemsetAsync(wsf, 0, (size_t)ZERO_FLOATS * sizeof(float), stream);

    // --- graph structure ---
    k_hist<<<E / 256, 256, 0, stream>>>(row, col, ew, E, deg, cntc, cntr, &scal[3]);
    k_dinv<<<N / 256, 256, 0, stream>>>(deg, dinv, N);
    k_scan<<<1, 1024, 0, stream>>>(cntc, cntr, cptr, rptr, curc, curr, N, E);
    k_scatter<<<E / 256, 256, 0, stream>>>(row, col, ew, E, dinv, curc, curr, colr, coln, rowc, roww);

    // --- level 0 GCN ---
    gemm_ab_b16<<<dim3(2, 128), 256, 0, stream>>>(x0, W0_in, h0b, 8192, 128, 128);
    k_agg_b16<<<N, 64, 0, stream>>>(h0b, x0_, x0b, cptr, colr, coln, dinv, b0_in, 1);

    // --- s1 = relu((M^T x0_)@Wp1 + bp1) ---
    k_agg_b16<<<N, 64, 0, stream>>>(x0b, nullptr, h0b, cptr, colr, coln, dinv, nullptr, 0);
    k_transpose_f2b<<<dim3(16, 2), 256, 0, stream>>>(Wp1, WP1T, 128, 1024, nullptr);
    gemm_tn_bf16_store<<<dim3(64, 8), 256, 0, stream>>>(h0b, WP1T, s1o, 8192, 1024, 128, bp1, 1);

    // --- diff_pool level 1 ---
    k_softmax1024<<<N, 256, 0, stream>>>(s1o, Sb, mask, &scal[0]);
    k_spmm_seg<<<dim3(N, 8), 64, 0, stream>>>(Sb, rptr, rowc, roww, TBF, &scal[1]);
    k_transpose_b2b<<<dim3(16, 128), 256, 0, stream>>>(Sb, ST, 8192, 1024);    // Sb dead after
    k_transpose_b2b<<<dim3(16, 128), 256, 0, stream>>>(TBF, TT, 8192, 1024);   // TT overwrites Sb region
    k_transpose_f2b<<<dim3(2, 128), 256, 0, stream>>>(x0_, X0T, 8192, 128, mask);

    gemm_tn_bf16_part<<<dim3(8, 8, 4), 256, 0, stream>>>(ST, TT, PADJ, 1024, 1024, 8192);
    gemm_tn_bf16_part<<<dim3(8, 8, 4), 256, 0, stream>>>(ST, ST, PG, 1024, 1024, 8192);
    gemm_tn_bf16_part<<<dim3(8, 1, 16), 256, 0, stream>>>(ST, X0T, PX1, 1024, 128, 8192);
    k_reduce4<<<1024, 256, 0, stream>>>(PADJ, adj1o, 1024 * 1024, 4, &scal[4]);  // adj1 + sum(adj1^2)
    k_reduce4<<<1024, 256, 0, stream>>>(PG, nullptr, 1024 * 1024, 4, &scal[2]);  // ||S^T S||^2
    k_reduce4<<<128, 256, 0, stream>>>(PX1, x1, 1024 * 128, 16, nullptr);        // x1

    // --- a_norm for adj1 ---
    k_colsum_part<<<dim3(4, 16), 256, 0, stream>>>(adj1o, 1024, cspart);
    k_dfix_part<<<4, 256, 0, stream>>>(adj1o, 1024, cspart, 16, di1, df1);
    k_anorm<<<4096, 256, 0, stream>>>(adj1o, 1024, di1, df1, an1);

    // --- level 1 dense GCNs ---
    gemm_ab32<<<dim3(4, 32), 256, 0, stream>>>(x1, W1_in, hA, 1024, 128, 128, nullptr, 0, 0);
    gemm_atb32<<<dim3(4, 32), 256, 0, stream>>>(an1, hA, x1_, 1024, 128, 1024, b1_in, 1, nullptr);
    gemm_ab32<<<dim3(4, 32), 256, 0, stream>>>(x1_, Wp2, hB, 1024, 128, 128, nullptr, 0, 0);
    gemm_atb32<<<dim3(4, 32), 256, 0, stream>>>(an1, hB, s2, 1024, 128, 1024, bp2, 1, nullptr);

    // --- diff_pool level 2 ---
    k_softmax_ent<<<1024, 256, 0, stream>>>(s2, S2s, 128, nullptr, &scal[5]);
    gemm_ab32<<<dim3(4, 32), 256, 0, stream>>>(adj1o, S2s, u, 1024, 128, 1024, nullptr, 0, 0);
    gemm_atb32<<<dim3(4, 4), 256, 0, stream>>>(S2s, x1_, x2, 128, 128, 1024, nullptr, 0, nullptr);
    gemm_atb32<<<dim3(4, 4), 256, 0, stream>>>(S2s, u, adj2, 128, 128, 1024, nullptr, 0, nullptr);
    // l2 = ||adj1 - S2 S2^T||^2 = sum(adj1^2) - 2*sum_i <S2_i, u_i> + ||S2^T S2||^2
    k_dot<<<64, 256, 0, stream>>>(S2s, u, 1024 * 128, &scal[6]);
    gemm_atb32<<<dim3(4, 4), 256, 0, stream>>>(S2s, S2s, nullptr, 128, 128, 1024, nullptr, 0, &scal[7]);

    // --- a_norm for adj2, level 2 GCN ---
    k_coldfix128<<<1, 128, 0, stream>>>(adj2, di2, df2);
    k_anorm<<<64, 256, 0, stream>>>(adj2, 128, di2, df2, an2);
    gemm_ab32<<<dim3(4, 4), 256, 0, stream>>>(x2, W2_in, hC, 128, 128, 128, nullptr, 0, 0);
    gemm_atb32<<<dim3(4, 4), 256, 0, stream>>>(an2, hC, x2_, 128, 128, 128, b2_in, 1, nullptr);

    // --- unpool to level 1:  hcat = x1_@W1o1 + s2@(x2_@W1o2) ---
    gemm_ab32<<<dim3(4, 4), 256, 0, stream>>>(x2_, W1_out + 128 * 128, z2, 128, 128, 128, nullptr, 0, 0);
    gemm_ab32<<<dim3(4, 32), 256, 0, stream>>>(x1_, W1_out, hcat, 1024, 128, 128, nullptr, 0, 0);
    gemm_ab32<<<dim3(4, 32), 256, 0, stream>>>(s2, z2, hcat, 1024, 128, 128, nullptr, 0, 1);
    gemm_atb32<<<dim3(4, 32), 256, 0, stream>>>(an1, hcat, x1o_, 1024, 128, 1024, b1_out, 1, nullptr);

    // --- unpool to level 0:  p16 = x0_@W0out1 + s1o@(x1o_@W0out2) ---
    k_gemm_n16<<<64, 256, 0, stream>>>(x1o_, W0_out + 128 * 16, hA /*=y*/, 1024, 128, 0);
    k_gemm_n16<<<512, 256, 0, stream>>>(x0_, W0_out, p16, 8192, 128, 0);
    k_gemm_n16<<<512, 256, 0, stream>>>(s1o, hA /*=y*/, p16, 8192, 1024, 1);
    k_agg16<<<512, 256, 0, stream>>>(p16, h16, cptr, colr, coln, dinv, b0_out);
    k_logsoftmax<<<32, 256, 0, stream>>>(h16, predo, N);

    k_finalize<<<1, 64, 0, stream>>>(scal, losso);
}

// Round 6
// 1269.592 us; speedup vs baseline: 1.5430x; 1.5430x over previous
//
#include <hip/hip_runtime.h>
#include <math.h>

// ---------------------------------------------------------------------------
// DiffPool GNN (N=8192, E=262144, F=H=128, C1=1024, C2=128, NC=16).
// R6: cross term = trace(adj1) (algebraic; kills 65536 contended atomics that
// made R5's spmm 842us); segmented SpMM restructured to 4 waves/block.
// ---------------------------------------------------------------------------

#define N_NODES 8192
#define N_EDGES 262144

typedef __attribute__((ext_vector_type(8))) short short8;
typedef __attribute__((ext_vector_type(4))) float floatx4;

// ---------------- workspace layout (float-slot offsets, 16-aligned) ----------------
#define OFF_DEG     0           // 8192  (zeroed)
#define OFF_CNTC    8192        // 8192  (zeroed)
#define OFF_CNTR    16384       // 8192  (zeroed)
#define OFF_SCAL    24576       // 16    (zeroed) [0]=e1 [1]=cross [2]=g2 [3]=sumA2
                                //                [4]=ss_adj1 [5]=e2 [6]=cross2 [7]=g2b
#define ZERO_FLOATS 24592
#define OFF_COLPTR  24592       // 8193
#define OFF_ROWPTR  32785       // 8193
#define OFF_CURC    40978       // 8192 (later: colsum partials, 16x1024 spans CURC+CURR)
#define OFF_CURR    49170       // 8192
#define OFF_COLR    57362       // E (int)
#define OFF_COLN    319506      // E
#define OFF_ROWC    581650      // E (int)
#define OFF_ROWW    843794      // E
#define OFF_DINV    1105938     // 8192
#define OFF_X0      1114144     // 8192*128 fp32 (x0_, live to the end)
#define OFF_H0      2162720     // h0b bf16 [8192][128]
// Region A:
#define OFF_S       3211296     // Sb bf16 [8192][1024]; then TT bf16; then an1 fp32
#define OFF_TT      OFF_S
#define OFF_AN1     OFF_S
#define OFF_X0T     7405600     // bf16 [128][8192]
#define OFF_X0B     7929888     // bf16 [8192][128]
#define A2          8454176
#define OFF_X1      (A2+0)            // 1024*128
#define OFF_HA      (A2+131072)       // 1024*128 (later: y 1024*16)
#define OFF_X1_     (A2+262144)
#define OFF_HB      (A2+393216)
#define OFF_S2      (A2+524288)
#define OFF_S2S     (A2+655360)
#define OFF_U       (A2+786432)
#define OFF_X2      (A2+917504)       // 128*128
#define OFF_ADJ2    (A2+933888)
#define OFF_HC      (A2+950272)
#define OFF_X2_     (A2+966656)
#define OFF_AN2     (A2+983040)
#define OFF_Z2      (A2+999424)       // 128*128
#define OFF_HCAT    (A2+1130496)      // 1024*128
#define OFF_X1O     (A2+1261568)      // 1024*128
#define OFF_P16     (A2+1392640)      // 8192*16
#define OFF_H16     (A2+1523712)
#define OFF_DI1     (A2+1654784)      // 1024
#define OFF_DF1     (A2+1655808)
#define OFF_DI2     (A2+1656832)      // 128
#define OFF_DF2     (A2+1656960)
// Region B:
#define OFF_ST      10111264          // S_T bf16 [1024][8192]
#define OFF_TBF     14305568          // t bf16 [8192][1024]; WP1T aliases start; later PADJ
#define OFF_WP1T    OFF_TBF
#define OFF_PADJ    OFF_TBF           // fp32 [4][1024][1024] (TBF dead by then)
#define OFF_PG      18499872          // fp32 [4][1024][1024]
#define OFF_PX1     22694176          // fp32 [16][1024][128]
// total: 24,791,328 float-slots = 94.6 MiB

// ------------------- output layout (floats) -------------------
#define OUT_PRED 0          // 8192*16
#define OUT_S1   131072     // 8192*1024
#define OUT_LOSS 8519680    // 1
#define OUT_ADJ1 8519681    // 1024*1024

__device__ __forceinline__ unsigned short f2bf(float f) {
    union { float f; unsigned u; } v; v.f = f;
    unsigned r = (v.u + 0x7FFF + ((v.u >> 16) & 1)) >> 16;
    return (unsigned short)r;
}
__device__ __forceinline__ float bf2f(unsigned short b) {
    union { unsigned u; float f; } v; v.u = (unsigned)b << 16; return v.f;
}

// =========================== graph-structure kernels ===========================

__global__ void k_hist(const int* __restrict__ row, const int* __restrict__ col,
                       const float* __restrict__ ew, int E,
                       float* deg, int* cntc, int* cntr, float* sumA2) {
    __shared__ float red[256];
    int e = blockIdx.x * 256 + threadIdx.x;
    float w2 = 0.f;
    if (e < E) {
        int r = row[e], c = col[e];
        float w = ew[e];
        atomicAdd(&deg[c], w);
        atomicAdd(&cntc[c], 1);
        atomicAdd(&cntr[r], 1);
        w2 = w * w;
    }
    red[threadIdx.x] = w2; __syncthreads();
    for (int s = 128; s > 0; s >>= 1) { if (threadIdx.x < s) red[threadIdx.x] += red[threadIdx.x + s]; __syncthreads(); }
    if (threadIdx.x == 0) atomicAdd(sumA2, red[0]);
}

__global__ void k_dinv(const float* deg, float* dinv, int n) {
    int i = blockIdx.x * 256 + threadIdx.x;
    if (i < n) {
        float d = deg[i] + 1.0f;
        dinv[i] = (d > 0.f) ? 1.0f / sqrtf(d) : 0.f;
    }
}

__global__ __launch_bounds__(1024) void k_scan(const int* cntc, const int* cntr,
        int* colptr, int* rowptr, int* curc, int* curr, int n, int E) {
    __shared__ int part[1024];
    int tid = threadIdx.x;
    const int per = 8;
    for (int pass = 0; pass < 2; ++pass) {
        const int* cnt = pass ? cntr : cntc;
        int* ptr = pass ? rowptr : colptr;
        int* cur = pass ? curr : curc;
        int st = tid * per;
        int loc[per]; int s = 0;
        for (int i = 0; i < per; ++i) { loc[i] = s; s += cnt[st + i]; }
        part[tid] = s; __syncthreads();
        for (int off = 1; off < 1024; off <<= 1) {
            int v = part[tid];
            int add = (tid >= off) ? part[tid - off] : 0;
            __syncthreads();
            part[tid] = v + add;
            __syncthreads();
        }
        int pre = (tid == 0) ? 0 : part[tid - 1];
        for (int i = 0; i < per; ++i) { int v = pre + loc[i]; ptr[st + i] = v; cur[st + i] = v; }
        if (tid == 0) ptr[n] = E;
        __syncthreads();
    }
}

__global__ void k_scatter(const int* __restrict__ row, const int* __restrict__ col,
                          const float* __restrict__ ew, int E, const float* __restrict__ dinv,
                          int* curc, int* curr, int* colr, float* coln, int* rowc, float* roww) {
    int e = blockIdx.x * 256 + threadIdx.x;
    if (e >= E) return;
    int r = row[e], c = col[e];
    float w = ew[e];
    float nrm = dinv[r] * w * dinv[c];
    int p = atomicAdd(&curc[c], 1);
    colr[p] = r; coln[p] = nrm;
    int q = atomicAdd(&curr[r], 1);
    rowc[q] = c; roww[q] = w;
}

// =========================== fp32 GEMMs ===========================

__global__ __launch_bounds__(256) void gemm_ab_b16(const float* __restrict__ A, const float* __restrict__ B,
        unsigned short* __restrict__ C, int M, int N, int K) {
    __shared__ float As[16][68];
    __shared__ float Bs[16][68];
    int tid = threadIdx.x, tx = tid & 15, ty = tid >> 4;
    int m0 = blockIdx.y * 64, n0 = blockIdx.x * 64;
    float acc[4][4] = {};
    for (int k0 = 0; k0 < K; k0 += 16) {
        for (int l = 0; l < 4; ++l) {
            int idx = tid + 256 * l;
            int mm = idx >> 4, kk = idx & 15;
            As[kk][mm] = A[(size_t)(m0 + mm) * K + k0 + kk];
            int kk2 = idx >> 6, nn = idx & 63;
            Bs[kk2][nn] = B[(size_t)(k0 + kk2) * N + n0 + nn];
        }
        __syncthreads();
        #pragma unroll
        for (int kk = 0; kk < 16; ++kk) {
            float a[4], b[4];
            #pragma unroll
            for (int i = 0; i < 4; ++i) a[i] = As[kk][ty * 4 + i];
            #pragma unroll
            for (int j = 0; j < 4; ++j) b[j] = Bs[kk][tx * 4 + j];
            #pragma unroll
            for (int i = 0; i < 4; ++i)
                #pragma unroll
                for (int j = 0; j < 4; ++j) acc[i][j] += a[i] * b[j];
        }
        __syncthreads();
    }
    for (int i = 0; i < 4; ++i)
        for (int j = 0; j < 4; ++j)
            C[(size_t)(m0 + ty * 4 + i) * N + n0 + tx * 4 + j] = f2bf(acc[i][j]);
}

__global__ __launch_bounds__(256) void gemm_ab32(const float* __restrict__ A, const float* __restrict__ B,
        float* __restrict__ C, int M, int N, int K,
        const float* __restrict__ bias, int relu, int accum) {
    __shared__ float As[32][33];
    __shared__ float Bs[32][33];
    int tid = threadIdx.x, tx = tid & 15, ty = tid >> 4;
    int m0 = blockIdx.y * 32, n0 = blockIdx.x * 32;
    float acc[2][2] = {};
    for (int k0 = 0; k0 < K; k0 += 32) {
        #pragma unroll
        for (int l = 0; l < 4; ++l) {
            int idx = tid + 256 * l;
            int r = idx >> 5, c = idx & 31;
            As[r][c] = A[(size_t)(m0 + r) * K + k0 + c];
            Bs[r][c] = B[(size_t)(k0 + r) * N + n0 + c];
        }
        __syncthreads();
        #pragma unroll
        for (int kk = 0; kk < 32; ++kk) {
            float a0 = As[ty * 2][kk], a1 = As[ty * 2 + 1][kk];
            float b0 = Bs[kk][tx * 2], b1 = Bs[kk][tx * 2 + 1];
            acc[0][0] += a0 * b0; acc[0][1] += a0 * b1;
            acc[1][0] += a1 * b0; acc[1][1] += a1 * b1;
        }
        __syncthreads();
    }
    #pragma unroll
    for (int i = 0; i < 2; ++i)
        #pragma unroll
        for (int j = 0; j < 2; ++j) {
            int m = m0 + ty * 2 + i, n = n0 + tx * 2 + j;
            float v = acc[i][j];
            if (accum) v += C[(size_t)m * N + n];
            if (bias) v += bias[n];
            if (relu) v = fmaxf(v, 0.f);
            C[(size_t)m * N + n] = v;
        }
}

__global__ __launch_bounds__(256) void gemm_atb32(const float* __restrict__ A, const float* __restrict__ B,
        float* __restrict__ C, int M, int N, int K,
        const float* __restrict__ bias, int relu, float* sumsq_acc) {
    __shared__ float As[32][33];
    __shared__ float Bs[32][33];
    __shared__ float red[256];
    int tid = threadIdx.x, tx = tid & 15, ty = tid >> 4;
    int m0 = blockIdx.y * 32, n0 = blockIdx.x * 32;
    float acc[2][2] = {};
    for (int k0 = 0; k0 < K; k0 += 32) {
        #pragma unroll
        for (int l = 0; l < 4; ++l) {
            int idx = tid + 256 * l;
            int r = idx >> 5, c = idx & 31;
            As[c][r] = A[(size_t)(k0 + r) * M + m0 + c];
            Bs[r][c] = B[(size_t)(k0 + r) * N + n0 + c];
        }
        __syncthreads();
        #pragma unroll
        for (int kk = 0; kk < 32; ++kk) {
            float a0 = As[ty * 2][kk], a1 = As[ty * 2 + 1][kk];
            float b0 = Bs[kk][tx * 2], b1 = Bs[kk][tx * 2 + 1];
            acc[0][0] += a0 * b0; acc[0][1] += a0 * b1;
            acc[1][0] += a1 * b0; acc[1][1] += a1 * b1;
        }
        __syncthreads();
    }
    if (sumsq_acc) {
        float ss = acc[0][0] * acc[0][0] + acc[0][1] * acc[0][1]
                 + acc[1][0] * acc[1][0] + acc[1][1] * acc[1][1];
        red[tid] = ss; __syncthreads();
        for (int s = 128; s > 0; s >>= 1) { if (tid < s) red[tid] += red[tid + s]; __syncthreads(); }
        if (tid == 0) atomicAdd(sumsq_acc, red[0]);
        return;
    }
    #pragma unroll
    for (int i = 0; i < 2; ++i)
        #pragma unroll
        for (int j = 0; j < 2; ++j) {
            int m = m0 + ty * 2 + i, n = n0 + tx * 2 + j;
            float v = acc[i][j];
            if (bias) v += bias[n];
            if (relu) v = fmaxf(v, 0.f);
            C[(size_t)m * N + n] = v;
        }
}

__global__ __launch_bounds__(256) void k_gemm_n16(const float* __restrict__ A, const float* __restrict__ B,
        float* __restrict__ C, int M, int K, int accum) {
    __shared__ float As[16][64];
    __shared__ float Bs[64][16];
    int tid = threadIdx.x;
    int r = tid >> 4, c = tid & 15;
    int m0 = blockIdx.x * 16;
    float acc = 0.f;
    for (int k0 = 0; k0 < K; k0 += 64) {
        #pragma unroll
        for (int l = 0; l < 4; ++l) {
            int idx = tid + 256 * l;
            int rr = idx >> 6, cc = idx & 63;
            As[rr][cc] = A[(size_t)(m0 + rr) * K + k0 + cc];
            int kk = idx >> 4, c2 = idx & 15;
            Bs[kk][c2] = B[(size_t)(k0 + kk) * 16 + c2];
        }
        __syncthreads();
        #pragma unroll 16
        for (int kk = 0; kk < 64; ++kk) acc += As[r][kk] * Bs[kk][c];
        __syncthreads();
    }
    float* p = &C[(size_t)(m0 + r) * 16 + c];
    if (accum) acc += *p;
    *p = acc;
}

// =========================== bf16 MFMA GEMMs ===========================

__global__ __launch_bounds__(256) void gemm_tn_bf16_part(
        const unsigned short* __restrict__ A, const unsigned short* __restrict__ B,
        float* __restrict__ P, int M, int N, int K) {
    __shared__ __align__(16) unsigned short As[128 * 64];
    __shared__ __align__(16) unsigned short Bs[128 * 64];
    int tid = threadIdx.x;
    int wave = tid >> 6, lane = tid & 63;
    int wm = wave >> 1, wn = wave & 1;
    int m0 = blockIdx.x * 128, n0 = blockIdx.y * 128;
    int kchunk = K / gridDim.z;
    int k0 = blockIdx.z * kchunk;
    float* Pz = P + (size_t)blockIdx.z * M * N;
    floatx4 acc[4][4] = {};
    int sr = tid >> 3;
    int sc = (tid & 7) * 8;
    int q = lane >> 4, lm = lane & 15;
    for (int kt = 0; kt < kchunk; kt += 64) {
        #pragma unroll
        for (int p = 0; p < 4; ++p) {
            int mrow = sr + p * 32;
            int gk = k0 + kt + sc;
            int scs = sc ^ ((mrow & 7) * 8);
            *(short8*)(&As[mrow * 64 + scs]) = *(const short8*)(&A[(size_t)(m0 + mrow) * K + gk]);
            *(short8*)(&Bs[mrow * 64 + scs]) = *(const short8*)(&B[(size_t)(n0 + mrow) * K + gk]);
        }
        __syncthreads();
        #pragma unroll
        for (int ks = 0; ks < 64; ks += 32) {
            short8 af[4], bf[4];
            int kk = ks + q * 8;
            #pragma unroll
            for (int i = 0; i < 4; ++i) {
                int ml = wm * 64 + i * 16 + lm;
                af[i] = *(const short8*)(&As[ml * 64 + (kk ^ ((ml & 7) * 8))]);
                int nl = wn * 64 + i * 16 + lm;
                bf[i] = *(const short8*)(&Bs[nl * 64 + (kk ^ ((nl & 7) * 8))]);
            }
            #pragma unroll
            for (int i = 0; i < 4; ++i)
                #pragma unroll
                for (int j = 0; j < 4; ++j)
                    acc[i][j] = __builtin_amdgcn_mfma_f32_16x16x32_bf16(af[i], bf[j], acc[i][j], 0, 0, 0);
        }
        __syncthreads();
    }
    for (int i = 0; i < 4; ++i) {
        int rowb = m0 + wm * 64 + i * 16 + q * 4;
        for (int j = 0; j < 4; ++j) {
            int col = n0 + wn * 64 + j * 16 + lm;
            #pragma unroll
            for (int r = 0; r < 4; ++r)
                Pz[(size_t)(rowb + r) * N + col] = acc[i][j][r];
        }
    }
}

__global__ __launch_bounds__(256) void gemm_tn_bf16_store(
        const unsigned short* __restrict__ A, const unsigned short* __restrict__ B,
        float* __restrict__ C, int M, int N, int K,
        const float* __restrict__ bias, int relu) {
    __shared__ __align__(16) unsigned short As[128 * 64];
    __shared__ __align__(16) unsigned short Bs[128 * 64];
    int tid = threadIdx.x;
    int wave = tid >> 6, lane = tid & 63;
    int wm = wave >> 1, wn = wave & 1;
    int m0 = blockIdx.x * 128, n0 = blockIdx.y * 128;
    floatx4 acc[4][4] = {};
    int sr = tid >> 3;
    int sc = (tid & 7) * 8;
    int q = lane >> 4, lm = lane & 15;
    for (int kt = 0; kt < K; kt += 64) {
        #pragma unroll
        for (int p = 0; p < 4; ++p) {
            int mrow = sr + p * 32;
            int gk = kt + sc;
            int scs = sc ^ ((mrow & 7) * 8);
            *(short8*)(&As[mrow * 64 + scs]) = *(const short8*)(&A[(size_t)(m0 + mrow) * K + gk]);
            *(short8*)(&Bs[mrow * 64 + scs]) = *(const short8*)(&B[(size_t)(n0 + mrow) * K + gk]);
        }
        __syncthreads();
        #pragma unroll
        for (int ks = 0; ks < 64; ks += 32) {
            short8 af[4], bf[4];
            int kk = ks + q * 8;
            #pragma unroll
            for (int i = 0; i < 4; ++i) {
                int ml = wm * 64 + i * 16 + lm;
                af[i] = *(const short8*)(&As[ml * 64 + (kk ^ ((ml & 7) * 8))]);
                int nl = wn * 64 + i * 16 + lm;
                bf[i] = *(const short8*)(&Bs[nl * 64 + (kk ^ ((nl & 7) * 8))]);
            }
            #pragma unroll
            for (int i = 0; i < 4; ++i)
                #pragma unroll
                for (int j = 0; j < 4; ++j)
                    acc[i][j] = __builtin_amdgcn_mfma_f32_16x16x32_bf16(af[i], bf[j], acc[i][j], 0, 0, 0);
        }
        __syncthreads();
    }
    for (int i = 0; i < 4; ++i) {
        int rowb = m0 + wm * 64 + i * 16 + q * 4;
        for (int j = 0; j < 4; ++j) {
            int col = n0 + wn * 64 + j * 16 + lm;
            float bv = bias ? bias[col] : 0.f;
            #pragma unroll
            for (int r = 0; r < 4; ++r) {
                float v = acc[i][j][r] + bv;
                if (relu) v = fmaxf(v, 0.f);
                C[(size_t)(rowb + r) * N + col] = v;
            }
        }
    }
}

__global__ __launch_bounds__(256) void k_reduce4(const float* __restrict__ P,
        float* __restrict__ C, int n, int nsplit, float* ss_acc) {
    __shared__ float red[256];
    float ss = 0.f;
    for (int i4 = (blockIdx.x * 256 + threadIdx.x) * 4; i4 < n; i4 += gridDim.x * 256 * 4) {
        float4 v = *(const float4*)(P + i4);
        for (int s = 1; s < nsplit; ++s) {
            float4 w = *(const float4*)(P + (size_t)s * n + i4);
            v.x += w.x; v.y += w.y; v.z += w.z; v.w += w.w;
        }
        if (C) *(float4*)(C + i4) = v;
        ss += v.x * v.x + v.y * v.y + v.z * v.z + v.w * v.w;
    }
    if (!ss_acc) return;
    red[threadIdx.x] = ss; __syncthreads();
    for (int s = 128; s > 0; s >>= 1) { if (threadIdx.x < s) red[threadIdx.x] += red[threadIdx.x + s]; __syncthreads(); }
    if (threadIdx.x == 0) atomicAdd(ss_acc, red[0]);
}

// cross = trace(adj1): single block, 256 threads over 1024 diag entries.
__global__ __launch_bounds__(256) void k_trace(const float* __restrict__ A, int n, float* acc) {
    __shared__ float red[256];
    float s = 0.f;
    for (int i = threadIdx.x; i < n; i += 256) s += A[(size_t)i * n + i];
    red[threadIdx.x] = s; __syncthreads();
    for (int st = 128; st > 0; st >>= 1) { if (threadIdx.x < st) red[threadIdx.x] += red[threadIdx.x + st]; __syncthreads(); }
    if (threadIdx.x == 0) *acc = red[0];
}

// =========================== transposes ===========================

__global__ __launch_bounds__(256) void k_transpose_f2b(
        const float* __restrict__ in, unsigned short* __restrict__ outb,
        int R, int C, const float* __restrict__ rowscale) {
    __shared__ float tile[64][65];
    int rb = blockIdx.y * 64, cb = blockIdx.x * 64;
    int t = threadIdx.x;
    int lr = t >> 4, lc4 = (t & 15) * 4;
    #pragma unroll
    for (int p = 0; p < 4; ++p) {
        int r = rb + lr + p * 16;
        float4 v = *(const float4*)(in + (size_t)r * C + cb + lc4);
        float s = rowscale ? rowscale[r] : 1.0f;
        tile[lr + p * 16][lc4 + 0] = v.x * s;
        tile[lr + p * 16][lc4 + 1] = v.y * s;
        tile[lr + p * 16][lc4 + 2] = v.z * s;
        tile[lr + p * 16][lc4 + 3] = v.w * s;
    }
    __syncthreads();
    int cc0 = t >> 5, rr = (t & 31) * 2;
    #pragma unroll
    for (int p = 0; p < 8; ++p) {
        int cc = cc0 + p * 8;
        unsigned a = f2bf(tile[rr][cc]);
        unsigned b = f2bf(tile[rr + 1][cc]);
        *(unsigned*)(outb + (size_t)(cb + cc) * R + rb + rr) = a | (b << 16);
    }
}

__global__ __launch_bounds__(256) void k_transpose_b2b(
        const unsigned short* __restrict__ in, unsigned short* __restrict__ out, int R, int C) {
    __shared__ __align__(16) unsigned short tile[64][72];
    int rb = blockIdx.y * 64, cb = blockIdx.x * 64;
    int t = threadIdx.x;
    int lr = t >> 3, lc = (t & 7) * 8;
    #pragma unroll
    for (int p = 0; p < 2; ++p) {
        int r = lr + p * 32;
        *(short8*)(&tile[r][lc]) = *(const short8*)(&in[(size_t)(rb + r) * C + cb + lc]);
    }
    __syncthreads();
    int cc0 = t >> 4, rr = (t & 15) * 4;
    #pragma unroll
    for (int p = 0; p < 4; ++p) {
        int cc = cc0 + p * 16;
        unsigned long long v = (unsigned long long)tile[rr][cc]
                             | ((unsigned long long)tile[rr + 1][cc] << 16)
                             | ((unsigned long long)tile[rr + 2][cc] << 32)
                             | ((unsigned long long)tile[rr + 3][cc] << 48);
        *(unsigned long long*)(&out[(size_t)(cb + cc) * R + rb + rr]) = v;
    }
}

// =========================== aggregation / misc ===========================

__global__ __launch_bounds__(64) void k_agg_b16(const unsigned short* __restrict__ h,
        float* __restrict__ out, unsigned short* __restrict__ outb,
        const int* __restrict__ cptr, const int* __restrict__ colr,
        const float* __restrict__ coln, const float* __restrict__ dinv,
        const float* __restrict__ bias, int relu) {
    int c = blockIdx.x, t = threadIdx.x;
    int f0 = t * 2;
    float d = dinv[c], dd = d * d;
    unsigned u = *(const unsigned*)(h + (size_t)c * 128 + f0);
    float a0 = dd * bf2f((unsigned short)(u & 0xffff));
    float a1 = dd * bf2f((unsigned short)(u >> 16));
    int e0 = cptr[c], e1 = cptr[c + 1];
    for (int e = e0; e < e1; ++e) {
        float w = coln[e];
        unsigned v = *(const unsigned*)(h + (size_t)colr[e] * 128 + f0);
        a0 += w * bf2f((unsigned short)(v & 0xffff));
        a1 += w * bf2f((unsigned short)(v >> 16));
    }
    if (bias) { a0 += bias[f0]; a1 += bias[f0 + 1]; }
    if (relu) { a0 = fmaxf(a0, 0.f); a1 = fmaxf(a1, 0.f); }
    if (out) { out[(size_t)c * 128 + f0] = a0; out[(size_t)c * 128 + f0 + 1] = a1; }
    if (outb) {
        unsigned o = (unsigned)f2bf(a0) | ((unsigned)f2bf(a1) << 16);
        *(unsigned*)(outb + (size_t)c * 128 + f0) = o;
    }
}

__global__ __launch_bounds__(256) void k_agg16(const float* __restrict__ h, float* __restrict__ out,
        const int* __restrict__ cptr, const int* __restrict__ colr,
        const float* __restrict__ coln, const float* __restrict__ dinv,
        const float* __restrict__ bias) {
    int node = blockIdx.x * 16 + (threadIdx.x >> 4);
    int f = threadIdx.x & 15;
    float d = dinv[node];
    float acc = d * d * h[(size_t)node * 16 + f];
    int e0 = cptr[node], e1 = cptr[node + 1];
    for (int e = e0; e < e1; ++e)
        acc += coln[e] * h[(size_t)colr[e] * 16 + f];
    acc += bias[f];
    out[(size_t)node * 16 + f] = fmaxf(acc, 0.f);
}

__global__ __launch_bounds__(256) void k_softmax1024(const float* __restrict__ x,
        unsigned short* __restrict__ Sb, const float* __restrict__ mask, float* ent_acc) {
    __shared__ float red[256];
    int r = blockIdx.x, tid = threadIdx.x;
    const float* xr = x + (size_t)r * 1024;
    float4 v = *(const float4*)(xr + tid * 4);
    float m = fmaxf(fmaxf(v.x, v.y), fmaxf(v.z, v.w));
    red[tid] = m; __syncthreads();
    for (int s = 128; s > 0; s >>= 1) { if (tid < s) red[tid] = fmaxf(red[tid], red[tid + s]); __syncthreads(); }
    m = red[0]; __syncthreads();
    float e0 = expf(v.x - m), e1 = expf(v.y - m), e2 = expf(v.z - m), e3 = expf(v.w - m);
    red[tid] = e0 + e1 + e2 + e3; __syncthreads();
    for (int s = 128; s > 0; s >>= 1) { if (tid < s) red[tid] += red[tid + s]; __syncthreads(); }
    float inv = 1.0f / red[0]; __syncthreads();
    float mk = mask ? mask[r] : 1.0f;
    float s0 = e0 * inv * mk, s1 = e1 * inv * mk, s2 = e2 * inv * mk, s3 = e3 * inv * mk;
    float ent = -(s0 * logf(s0 + 1e-15f) + s1 * logf(s1 + 1e-15f)
                + s2 * logf(s2 + 1e-15f) + s3 * logf(s3 + 1e-15f));
    ushort4 o;
    o.x = f2bf(s0); o.y = f2bf(s1); o.z = f2bf(s2); o.w = f2bf(s3);
    *(ushort4*)(Sb + (size_t)r * 1024 + tid * 4) = o;
    red[tid] = ent; __syncthreads();
    for (int s = 128; s > 0; s >>= 1) { if (tid < s) red[tid] += red[tid + s]; __syncthreads(); }
    if (tid == 0) atomicAdd(ent_acc, red[0]);
}

__global__ __launch_bounds__(256) void k_softmax_ent(const float* __restrict__ x, float* __restrict__ S,
        int W, const float* __restrict__ mask, float* ent_acc) {
    __shared__ float red[256];
    int row = blockIdx.x, tid = threadIdx.x;
    const float* xr = x + (size_t)row * W;
    float m = -3.0e38f;
    for (int q = tid; q < W; q += 256) m = fmaxf(m, xr[q]);
    red[tid] = m; __syncthreads();
    for (int s = 128; s > 0; s >>= 1) { if (tid < s) red[tid] = fmaxf(red[tid], red[tid + s]); __syncthreads(); }
    m = red[0]; __syncthreads();
    float sum = 0.f;
    for (int q = tid; q < W; q += 256) sum += expf(xr[q] - m);
    red[tid] = sum; __syncthreads();
    for (int s = 128; s > 0; s >>= 1) { if (tid < s) red[tid] += red[tid + s]; __syncthreads(); }
    float inv = 1.0f / red[0]; __syncthreads();
    float mk = mask ? mask[row] : 1.0f;
    float* Sr = S + (size_t)row * W;
    float ent = 0.f;
    for (int q = tid; q < W; q += 256) {
        float v = expf(xr[q] - m) * inv * mk;
        Sr[q] = v;
        ent -= v * logf(v + 1e-15f);
    }
    red[tid] = ent; __syncthreads();
    for (int s = 128; s > 0; s >>= 1) { if (tid < s) red[tid] += red[tid + s]; __syncthreads(); }
    if (tid == 0) atomicAdd(ent_acc, red[0]);
}

// L2-segmented SpMM, 4 waves/block = 4 rows, pass p = cols [p*128, p*128+128).
// No scalar reduction (cross = trace(adj1), computed separately).
__global__ __launch_bounds__(256) void k_spmm_seg(const unsigned short* __restrict__ Sb,
        const int* __restrict__ rptr, const int* __restrict__ rowc, const float* __restrict__ roww,
        unsigned short* __restrict__ tb) {
    int wave = threadIdx.x >> 6, lane = threadIdx.x & 63;
    int r = blockIdx.x * 4 + wave;
    int j0 = blockIdx.y * 128 + lane * 2;
    float a0 = 0.f, a1 = 0.f;
    int e0 = rptr[r], e1 = rptr[r + 1];
    for (int e = e0; e < e1; ++e) {
        int c = rowc[e]; float w = roww[e];
        unsigned v = *(const unsigned*)(Sb + (size_t)c * 1024 + j0);
        a0 += w * bf2f((unsigned short)(v & 0xffff));
        a1 += w * bf2f((unsigned short)(v >> 16));
    }
    unsigned o = (unsigned)f2bf(a0) | ((unsigned)f2bf(a1) << 16);
    *(unsigned*)(tb + (size_t)r * 1024 + j0) = o;
}

__global__ void k_colsum_part(const float* __restrict__ adjm, int n, float* part) {
    int j = blockIdx.x * blockDim.x + threadIdx.x;
    if (j >= n) return;
    int r0 = blockIdx.y * 64;
    float s = 0.f;
    for (int r = r0; r < r0 + 64; ++r) s += adjm[(size_t)r * n + j];
    part[(size_t)blockIdx.y * n + j] = s;
}

__global__ void k_dfix_part(const float* __restrict__ adjm, int n, const float* __restrict__ part,
                            int nparts, float* dinvv, float* dfix) {
    int j = blockIdx.x * blockDim.x + threadIdx.x;
    if (j >= n) return;
    float s = 0.f;
    for (int p = 0; p < nparts; ++p) s += part[(size_t)p * n + j];
    float diag = adjm[(size_t)j * n + j];
    float fix = (diag == 0.f) ? 1.0f : 0.f;
    s += fix;
    dfix[j] = fix;
    dinvv[j] = (s > 0.f) ? 1.0f / sqrtf(s) : 0.f;
}

__global__ __launch_bounds__(128) void k_coldfix128(const float* __restrict__ adjm,
        float* dinvv, float* dfix) {
    int j = threadIdx.x;
    float s = 0.f;
    for (int i = 0; i < 128; ++i) s += adjm[(size_t)i * 128 + j];
    float diag = adjm[(size_t)j * 128 + j];
    float fix = (diag == 0.f) ? 1.0f : 0.f;
    s += fix;
    dfix[j] = fix;
    dinvv[j] = (s > 0.f) ? 1.0f / sqrtf(s) : 0.f;
}

__global__ void k_anorm(const float* __restrict__ adjm, int n, const float* __restrict__ dinvv,
                        const float* __restrict__ dfix, float* __restrict__ anorm) {
    int idx = blockIdx.x * 256 + threadIdx.x;
    if (idx >= n * n) return;
    int i = idx / n, j = idx % n;
    float v = adjm[idx] + ((i == j) ? dfix[j] : 0.f);
    anorm[idx] = dinvv[i] * v * dinvv[j];
}

__global__ __launch_bounds__(256) void k_dot(const float* __restrict__ a, const float* __restrict__ b,
        int n, float* acc) {
    __shared__ float red[256];
    float s = 0.f;
    for (int i = blockIdx.x * 256 + threadIdx.x; i < n; i += gridDim.x * 256) s += a[i] * b[i];
    red[threadIdx.x] = s; __syncthreads();
    for (int st = 128; st > 0; st >>= 1) { if (threadIdx.x < st) red[threadIdx.x] += red[threadIdx.x + st]; __syncthreads(); }
    if (threadIdx.x == 0) atomicAdd(acc, red[0]);
}

__global__ void k_logsoftmax(const float* __restrict__ x, float* __restrict__ out, int n) {
    int i = blockIdx.x * 256 + threadIdx.x;
    if (i >= n) return;
    float v[16];
    float m = -3.0e38f;
    #pragma unroll
    for (int j = 0; j < 16; ++j) { v[j] = x[(size_t)i * 16 + j]; m = fmaxf(m, v[j]); }
    float s = 0.f;
    #pragma unroll
    for (int j = 0; j < 16; ++j) s += expf(v[j] - m);
    float ls = m + logf(s);
    #pragma unroll
    for (int j = 0; j < 16; ++j) out[(size_t)i * 16 + j] = v[j] - ls;
}

__global__ void k_finalize(const float* __restrict__ sc, float* loss) {
    if (threadIdx.x == 0 && blockIdx.x == 0) {
        float e1     = sc[0] / 8192.0f;
        float cross  = sc[1];
        float g2     = sc[2];
        float sumA2  = sc[3];
        float ssadj1 = sc[4];
        float e2     = sc[5] / 1024.0f;
        float cross2 = sc[6];
        float g2b    = sc[7];
        float l1 = sqrtf(fmaxf(sumA2 - 2.0f * cross + g2, 0.f)) / 67108864.0f;
        float l2 = sqrtf(fmaxf(ssadj1 - 2.0f * cross2 + g2b, 0.f)) / 1048576.0f;
        *loss = l1 + e1 + l2 + e2;
    }
}

// =========================== launcher ===========================

extern "C" void kernel_launch(void* const* d_in, const int* in_sizes, int n_in,
                              void* d_out, int out_size, void* d_ws, size_t ws_size,
                              hipStream_t stream) {
    const int N = N_NODES, E = N_EDGES;
    const float* x0     = (const float*)d_in[0];
    const int*   eidx   = (const int*)d_in[1];
    const float* ew     = (const float*)d_in[2];
    const float* mask   = (const float*)d_in[4];
    const float* W0_in  = (const float*)d_in[5];
    const float* b0_in  = (const float*)d_in[6];
    const float* Wp1    = (const float*)d_in[7];
    const float* bp1    = (const float*)d_in[8];
    const float* W1_in  = (const float*)d_in[9];
    const float* b1_in  = (const float*)d_in[10];
    const float* Wp2    = (const float*)d_in[11];
    const float* bp2    = (const float*)d_in[12];
    const float* W2_in  = (const float*)d_in[13];
    const float* b2_in  = (const float*)d_in[14];
    const float* W1_out = (const float*)d_in[15];
    const float* b1_out = (const float*)d_in[16];
    const float* W0_out = (const float*)d_in[17];
    const float* b0_out = (const float*)d_in[18];

    float* out   = (float*)d_out;
    float* predo = out + OUT_PRED;
    float* s1o   = out + OUT_S1;
    float* losso = out + OUT_LOSS;
    float* adj1o = out + OUT_ADJ1;

    float* wsf = (float*)d_ws;
    int*   wsi = (int*)d_ws;
    float* deg   = wsf + OFF_DEG;
    int*   cntc  = wsi + OFF_CNTC;
    int*   cntr  = wsi + OFF_CNTR;
    float* scal  = wsf + OFF_SCAL;
    int*   cptr  = wsi + OFF_COLPTR;
    int*   rptr  = wsi + OFF_ROWPTR;
    int*   curc  = wsi + OFF_CURC;
    int*   curr  = wsi + OFF_CURR;
    int*   colr  = wsi + OFF_COLR;
    float* coln  = wsf + OFF_COLN;
    int*   rowc  = wsi + OFF_ROWC;
    float* roww  = wsf + OFF_ROWW;
    float* dinv  = wsf + OFF_DINV;
    float* x0_   = wsf + OFF_X0;
    unsigned short* h0b  = (unsigned short*)(wsf + OFF_H0);
    unsigned short* Sb   = (unsigned short*)(wsf + OFF_S);
    unsigned short* TT   = (unsigned short*)(wsf + OFF_TT);
    unsigned short* ST   = (unsigned short*)(wsf + OFF_ST);
    unsigned short* TBF  = (unsigned short*)(wsf + OFF_TBF);
    unsigned short* WP1T = (unsigned short*)(wsf + OFF_WP1T);
    unsigned short* X0T  = (unsigned short*)(wsf + OFF_X0T);
    unsigned short* x0b  = (unsigned short*)(wsf + OFF_X0B);
    float* an1   = wsf + OFF_AN1;
    float* PADJ  = wsf + OFF_PADJ;
    float* PG    = wsf + OFF_PG;
    float* PX1   = wsf + OFF_PX1;
    float* x1    = wsf + OFF_X1;
    float* hA    = wsf + OFF_HA;
    float* x1_   = wsf + OFF_X1_;
    float* hB    = wsf + OFF_HB;
    float* s2    = wsf + OFF_S2;
    float* S2s   = wsf + OFF_S2S;
    float* u     = wsf + OFF_U;
    float* x2    = wsf + OFF_X2;
    float* adj2  = wsf + OFF_ADJ2;
    float* hC    = wsf + OFF_HC;
    float* x2_   = wsf + OFF_X2_;
    float* an2   = wsf + OFF_AN2;
    float* z2    = wsf + OFF_Z2;
    float* hcat  = wsf + OFF_HCAT;
    float* x1o_  = wsf + OFF_X1O;
    float* p16   = wsf + OFF_P16;
    float* h16   = wsf + OFF_H16;
    float* di1   = wsf + OFF_DI1;
    float* df1   = wsf + OFF_DF1;
    float* di2   = wsf + OFF_DI2;
    float* df2   = wsf + OFF_DF2;
    float* cspart = wsf + OFF_CURC;

    const int* row = eidx;
    const int* col = eidx + E;

    hipMemsetAsync(wsf, 0, (size_t)ZERO_FLOATS * sizeof(float), stream);

    // --- graph structure ---
    k_hist<<<E / 256, 256, 0, stream>>>(row, col, ew, E, deg, cntc, cntr, &scal[3]);
    k_dinv<<<N / 256, 256, 0, stream>>>(deg, dinv, N);
    k_scan<<<1, 1024, 0, stream>>>(cntc, cntr, cptr, rptr, curc, curr, N, E);
    k_scatter<<<E / 256, 256, 0, stream>>>(row, col, ew, E, dinv, curc, curr, colr, coln, rowc, roww);

    // --- level 0 GCN ---
    gemm_ab_b16<<<dim3(2, 128), 256, 0, stream>>>(x0, W0_in, h0b, 8192, 128, 128);
    k_agg_b16<<<N, 64, 0, stream>>>(h0b, x0_, x0b, cptr, colr, coln, dinv, b0_in, 1);

    // --- s1 = relu((M^T x0_)@Wp1 + bp1) ---
    k_agg_b16<<<N, 64, 0, stream>>>(x0b, nullptr, h0b, cptr, colr, coln, dinv, nullptr, 0);
    k_transpose_f2b<<<dim3(16, 2), 256, 0, stream>>>(Wp1, WP1T, 128, 1024, nullptr);
    gemm_tn_bf16_store<<<dim3(64, 8), 256, 0, stream>>>(h0b, WP1T, s1o, 8192, 1024, 128, bp1, 1);

    // --- diff_pool level 1 ---
    k_softmax1024<<<N, 256, 0, stream>>>(s1o, Sb, mask, &scal[0]);
    k_spmm_seg<<<dim3(N / 4, 8), 256, 0, stream>>>(Sb, rptr, rowc, roww, TBF);
    k_transpose_b2b<<<dim3(16, 128), 256, 0, stream>>>(Sb, ST, 8192, 1024);    // Sb dead after
    k_transpose_b2b<<<dim3(16, 128), 256, 0, stream>>>(TBF, TT, 8192, 1024);   // TT overwrites Sb region
    k_transpose_f2b<<<dim3(2, 128), 256, 0, stream>>>(x0_, X0T, 8192, 128, mask);

    gemm_tn_bf16_part<<<dim3(8, 8, 4), 256, 0, stream>>>(ST, TT, PADJ, 1024, 1024, 8192);
    gemm_tn_bf16_part<<<dim3(8, 8, 4), 256, 0, stream>>>(ST, ST, PG, 1024, 1024, 8192);
    gemm_tn_bf16_part<<<dim3(8, 1, 16), 256, 0, stream>>>(ST, X0T, PX1, 1024, 128, 8192);
    k_reduce4<<<1024, 256, 0, stream>>>(PADJ, adj1o, 1024 * 1024, 4, &scal[4]);  // adj1 + sum(adj1^2)
    k_reduce4<<<1024, 256, 0, stream>>>(PG, nullptr, 1024 * 1024, 4, &scal[2]);  // ||S^T S||^2
    k_reduce4<<<128, 256, 0, stream>>>(PX1, x1, 1024 * 128, 16, nullptr);        // x1
    k_trace<<<1, 256, 0, stream>>>(adj1o, 1024, &scal[1]);                       // cross = tr(adj1)

    // --- a_norm for adj1 ---
    k_colsum_part<<<dim3(4, 16), 256, 0, stream>>>(adj1o, 1024, cspart);
    k_dfix_part<<<4, 256, 0, stream>>>(adj1o, 1024, cspart, 16, di1, df1);
    k_anorm<<<4096, 256, 0, stream>>>(adj1o, 1024, di1, df1, an1);

    // --- level 1 dense GCNs ---
    gemm_ab32<<<dim3(4, 32), 256, 0, stream>>>(x1, W1_in, hA, 1024, 128, 128, nullptr, 0, 0);
    gemm_atb32<<<dim3(4, 32), 256, 0, stream>>>(an1, hA, x1_, 1024, 128, 1024, b1_in, 1, nullptr);
    gemm_ab32<<<dim3(4, 32), 256, 0, stream>>>(x1_, Wp2, hB, 1024, 128, 128, nullptr, 0, 0);
    gemm_atb32<<<dim3(4, 32), 256, 0, stream>>>(an1, hB, s2, 1024, 128, 1024, bp2, 1, nullptr);

    // --- diff_pool level 2 ---
    k_softmax_ent<<<1024, 256, 0, stream>>>(s2, S2s, 128, nullptr, &scal[5]);
    gemm_ab32<<<dim3(4, 32), 256, 0, stream>>>(adj1o, S2s, u, 1024, 128, 1024, nullptr, 0, 0);
    gemm_atb32<<<dim3(4, 4), 256, 0, stream>>>(S2s, x1_, x2, 128, 128, 1024, nullptr, 0, nullptr);
    gemm_atb32<<<dim3(4, 4), 256, 0, stream>>>(S2s, u, adj2, 128, 128, 1024, nullptr, 0, nullptr);
    // l2 = sum(adj1^2) - 2*<S2s, u> + ||S2^T S2||^2
    k_dot<<<64, 256, 0, stream>>>(S2s, u, 1024 * 128, &scal[6]);
    gemm_atb32<<<dim3(4, 4), 256, 0, stream>>>(S2s, S2s, nullptr, 128, 128, 1024, nullptr, 0, &scal[7]);

    // --- a_norm for adj2, level 2 GCN ---
    k_coldfix128<<<1, 128, 0, stream>>>(adj2, di2, df2);
    k_anorm<<<64, 256, 0, stream>>>(adj2, 128, di2, df2, an2);
    gemm_ab32<<<dim3(4, 4), 256, 0, stream>>>(x2, W2_in, hC, 128, 128, 128, nullptr, 0, 0);
    gemm_atb32<<<dim3(4, 4), 256, 0, stream>>>(an2, hC, x2_, 128, 128, 128, b2_in, 1, nullptr);

    // --- unpool to level 1:  hcat = x1_@W1o1 + s2@(x2_@W1o2) ---
    gemm_ab32<<<dim3(4, 4), 256, 0, stream>>>(x2_, W1_out + 128 * 128, z2, 128, 128, 128, nullptr, 0, 0);
    gemm_ab32<<<dim3(4, 32), 256, 0, stream>>>(x1_, W1_out, hcat, 1024, 128, 128, nullptr, 0, 0);
    gemm_ab32<<<dim3(4, 32), 256, 0, stream>>>(s2, z2, hcat, 1024, 128, 128, nullptr, 0, 1);
    gemm_atb32<<<dim3(4, 32), 256, 0, stream>>>(an1, hcat, x1o_, 1024, 128, 1024, b1_out, 1, nullptr);

    // --- unpool to level 0:  p16 = x0_@W0out1 + s1o@(x1o_@W0out2) ---
    k_gemm_n16<<<64, 256, 0, stream>>>(x1o_, W0_out + 128 * 16, hA /*=y*/, 1024, 128, 0);
    k_gemm_n16<<<512, 256, 0, stream>>>(x0_, W0_out, p16, 8192, 128, 0);
    k_gemm_n16<<<512, 256, 0, stream>>>(s1o, hA /*=y*/, p16, 8192, 1024, 1);
    k_agg16<<<512, 256, 0, stream>>>(p16, h16, cptr, colr, coln, dinv, b0_out);
    k_logsoftmax<<<32, 256, 0, stream>>>(h16, predo, N);

    k_finalize<<<1, 64, 0, stream>>>(scal, losso);
}

// Round 9
// 1171.600 us; speedup vs baseline: 1.6720x; 1.0836x over previous
//
#include <hip/hip_runtime.h>
#include <math.h>

// ---------------------------------------------------------------------------
// DiffPool GNN (N=8192, E=262144, F=H=128, C1=1024, C2=128, NC=16).
// R9 (= R8 design, compile-safe): mid-chain K=1024 gemms -> bf16 MFMA split-K
// (an1 kept only as bf16^T); producers emit bf16-transposed outputs via
// single-source kernels; trace/dinv/logsoftmax fused into neighbors.
// ---------------------------------------------------------------------------

#define N_NODES 8192
#define N_EDGES 262144

typedef __attribute__((ext_vector_type(8))) short short8;
typedef __attribute__((ext_vector_type(4))) float floatx4;

// ---------------- workspace layout (float-slot offsets, 16-aligned) ----------------
#define OFF_DEG     0           // 8192  (zeroed)
#define OFF_CNTC    8192        // 8192  (zeroed)
#define OFF_CNTR    16384       // 8192  (zeroed)
#define OFF_SCAL    24576       // 16 (zeroed) [0]=e1 [1]=cross(tr adj1) [2]=g2 [3]=sumA2
                                //             [4]=ss_adj1 [5]=e2 [6]=cross2(tr adj2) [7]=g2b
#define ZERO_FLOATS 24592
#define OFF_COLPTR  24592       // 8193
#define OFF_ROWPTR  32785       // 8193
#define OFF_CURC    40978       // 8192 (later: colsum partials 16x1024 span CURC+CURR)
#define OFF_CURR    49170       // 8192
#define OFF_COLR    57362       // E (int)
#define OFF_COLN    319506      // E
#define OFF_ROWC    581650      // E (int)
#define OFF_ROWW    843794      // E
#define OFF_DINV    1105938     // 8192
#define OFF_X0      1114144     // 8192*128 fp32 (x0_)
#define OFF_H0      2162720     // h0b bf16 [8192][128]
// Region A (4M slots at OFF_S: Sb -> TT -> {an1Tb, adj1b, hats...}):
#define OFF_S       3211296     // Sb bf16 [8192][1024]
#define OFF_TT      OFF_S
#define OFF_AN1TB   OFF_S                 // bf16 [1024][1024] (after TT dead)
#define OFF_ADJ1B   (OFF_S+524288)        // bf16 [1024][1024]
#define OFF_HAT     (OFF_S+1048576)       // bf16 [128][1024]
#define OFF_HBT     (OFF_S+1114112)       // bf16 [128][1024]
#define OFF_HCATT   (OFF_S+1179648)       // bf16 [128][1024]
#define OFF_S2ST    (OFF_S+1245184)       // bf16 [128][1024]
#define OFF_X0T     7405600     // bf16 [128][8192]
#define OFF_X0B     7929888     // bf16 [8192][128]
#define A2          8454176
#define OFF_X1      (A2+0)            // 1024*128
#define OFF_Y16     (A2+131072)       // 1024*16
#define OFF_X1_     (A2+262144)       // 1024*128
#define OFF_S2      (A2+524288)       // 1024*128
#define OFF_S2S     (A2+655360)       // 1024*128
#define OFF_U       (A2+786432)       // 1024*128
#define OFF_X2      (A2+917504)       // 128*128
#define OFF_ADJ2    (A2+933888)
#define OFF_HC      (A2+950272)
#define OFF_X2_     (A2+966656)
#define OFF_AN2     (A2+983040)
#define OFF_Z2      (A2+999424)       // 128*128
#define OFF_HCAT    (A2+1130496)      // 1024*128 fp32
#define OFF_X1O     (A2+1261568)      // 1024*128
#define OFF_P16     (A2+1392640)      // 8192*16
#define OFF_DI1     (A2+1654784)      // 1024
#define OFF_DF1     (A2+1655808)
#define OFF_DI2     (A2+1656832)      // 128
#define OFF_DF2     (A2+1656960)
// Region B:
#define OFF_ST      10111264          // S_T bf16 [1024][8192]
#define OFF_TBF     14305568          // t bf16 [8192][1024]; WP1T aliases; later PADJ
#define OFF_WP1T    OFF_TBF
#define OFF_PADJ    OFF_TBF           // fp32 [4][1024][1024]
#define OFF_PG      18499872          // fp32 [4][1024][1024]; later PP fp32 [8][1024][128]
#define OFF_PP      OFF_PG
#define OFF_PX1     22694176          // fp32 [16][1024][128]
// total: 24,791,328 float-slots = 94.6 MiB

// ------------------- output layout (floats) -------------------
#define OUT_PRED 0          // 8192*16
#define OUT_S1   131072     // 8192*1024
#define OUT_LOSS 8519680    // 1
#define OUT_ADJ1 8519681    // 1024*1024

__device__ __forceinline__ unsigned short f2bf(float f) {
    union { float f; unsigned u; } v; v.f = f;
    unsigned r = (v.u + 0x7FFF + ((v.u >> 16) & 1)) >> 16;
    return (unsigned short)r;
}
__device__ __forceinline__ float bf2f(unsigned short b) {
    union { unsigned u; float f; } v; v.u = (unsigned)b << 16; return v.f;
}

// =========================== graph-structure kernels ===========================

__global__ void k_hist(const int* __restrict__ row, const int* __restrict__ col,
                       const float* __restrict__ ew, int E,
                       float* deg, int* cntc, int* cntr, float* sumA2) {
    __shared__ float red[256];
    int e = blockIdx.x * 256 + threadIdx.x;
    float w2 = 0.f;
    if (e < E) {
        int r = row[e], c = col[e];
        float w = ew[e];
        atomicAdd(&deg[c], w);
        atomicAdd(&cntc[c], 1);
        atomicAdd(&cntr[r], 1);
        w2 = w * w;
    }
    red[threadIdx.x] = w2; __syncthreads();
    for (int s = 128; s > 0; s >>= 1) { if (threadIdx.x < s) red[threadIdx.x] += red[threadIdx.x + s]; __syncthreads(); }
    if (threadIdx.x == 0) atomicAdd(sumA2, red[0]);
}

// scan of both count arrays + dinv (fused)
__global__ __launch_bounds__(1024) void k_scan(const int* cntc, const int* cntr,
        int* colptr, int* rowptr, int* curc, int* curr, int n, int E,
        const float* __restrict__ deg, float* __restrict__ dinv) {
    __shared__ int part[1024];
    int tid = threadIdx.x;
    const int per = 8;
    for (int pass = 0; pass < 2; ++pass) {
        const int* cnt = pass ? cntr : cntc;
        int* ptr = pass ? rowptr : colptr;
        int* cur = pass ? curr : curc;
        int st = tid * per;
        int loc[per]; int s = 0;
        for (int i = 0; i < per; ++i) { loc[i] = s; s += cnt[st + i]; }
        part[tid] = s; __syncthreads();
        for (int off = 1; off < 1024; off <<= 1) {
            int v = part[tid];
            int add = (tid >= off) ? part[tid - off] : 0;
            __syncthreads();
            part[tid] = v + add;
            __syncthreads();
        }
        int pre = (tid == 0) ? 0 : part[tid - 1];
        for (int i = 0; i < per; ++i) { int v = pre + loc[i]; ptr[st + i] = v; cur[st + i] = v; }
        if (tid == 0) ptr[n] = E;
        __syncthreads();
    }
    for (int i = tid; i < n; i += 1024) {
        float d = deg[i] + 1.0f;
        dinv[i] = (d > 0.f) ? 1.0f / sqrtf(d) : 0.f;
    }
}

__global__ void k_scatter(const int* __restrict__ row, const int* __restrict__ col,
                          const float* __restrict__ ew, int E, const float* __restrict__ dinv,
                          int* curc, int* curr, int* colr, float* coln, int* rowc, float* roww) {
    int e = blockIdx.x * 256 + threadIdx.x;
    if (e >= E) return;
    int r = row[e], c = col[e];
    float w = ew[e];
    float nrm = dinv[r] * w * dinv[c];
    int p = atomicAdd(&curc[c], 1);
    colr[p] = r; coln[p] = nrm;
    int q = atomicAdd(&curr[r], 1);
    rowc[q] = c; roww[q] = w;
}

// =========================== fp32 GEMMs ===========================

__global__ __launch_bounds__(256) void gemm_ab_b16(const float* __restrict__ A, const float* __restrict__ B,
        unsigned short* __restrict__ C, int M, int N, int K) {
    __shared__ float As[16][68];
    __shared__ float Bs[16][68];
    int tid = threadIdx.x, tx = tid & 15, ty = tid >> 4;
    int m0 = blockIdx.y * 64, n0 = blockIdx.x * 64;
    float acc[4][4] = {};
    for (int k0 = 0; k0 < K; k0 += 16) {
        for (int l = 0; l < 4; ++l) {
            int idx = tid + 256 * l;
            int mm = idx >> 4, kk = idx & 15;
            As[kk][mm] = A[(size_t)(m0 + mm) * K + k0 + kk];
            int kk2 = idx >> 6, nn = idx & 63;
            Bs[kk2][nn] = B[(size_t)(k0 + kk2) * N + n0 + nn];
        }
        __syncthreads();
        #pragma unroll
        for (int kk = 0; kk < 16; ++kk) {
            float a[4], b[4];
            #pragma unroll
            for (int i = 0; i < 4; ++i) a[i] = As[kk][ty * 4 + i];
            #pragma unroll
            for (int j = 0; j < 4; ++j) b[j] = Bs[kk][tx * 4 + j];
            #pragma unroll
            for (int i = 0; i < 4; ++i)
                #pragma unroll
                for (int j = 0; j < 4; ++j) acc[i][j] += a[i] * b[j];
        }
        __syncthreads();
    }
    for (int i = 0; i < 4; ++i)
        for (int j = 0; j < 4; ++j)
            C[(size_t)(m0 + ty * 4 + i) * N + n0 + tx * 4 + j] = f2bf(acc[i][j]);
}

// 32x32 tile, C = A@B (+bias/relu/accum), fp32 out
__global__ __launch_bounds__(256) void gemm_ab32(const float* __restrict__ A, const float* __restrict__ B,
        float* __restrict__ C, int M, int N, int K,
        const float* __restrict__ bias, int relu, int accum) {
    __shared__ float As[32][33];
    __shared__ float Bs[32][33];
    int tid = threadIdx.x, tx = tid & 15, ty = tid >> 4;
    int m0 = blockIdx.y * 32, n0 = blockIdx.x * 32;
    float acc[2][2] = {};
    for (int k0 = 0; k0 < K; k0 += 32) {
        #pragma unroll
        for (int l = 0; l < 4; ++l) {
            int idx = tid + 256 * l;
            int r = idx >> 5, c = idx & 31;
            As[r][c] = A[(size_t)(m0 + r) * K + k0 + c];
            Bs[r][c] = B[(size_t)(k0 + r) * N + n0 + c];
        }
        __syncthreads();
        #pragma unroll
        for (int kk = 0; kk < 32; ++kk) {
            float a0 = As[ty * 2][kk], a1 = As[ty * 2 + 1][kk];
            float b0 = Bs[kk][tx * 2], b1 = Bs[kk][tx * 2 + 1];
            acc[0][0] += a0 * b0; acc[0][1] += a0 * b1;
            acc[1][0] += a1 * b0; acc[1][1] += a1 * b1;
        }
        __syncthreads();
    }
    #pragma unroll
    for (int i = 0; i < 2; ++i)
        #pragma unroll
        for (int j = 0; j < 2; ++j) {
            int m = m0 + ty * 2 + i, n = n0 + tx * 2 + j;
            float v = acc[i][j];
            if (accum) v += C[(size_t)m * N + n];
            if (bias) v += bias[n];
            if (relu) v = fmaxf(v, 0.f);
            C[(size_t)m * N + n] = v;
        }
}

// 32x32 tile: CT[N][M] bf16 = (A@B)^T, single-source
__global__ __launch_bounds__(256) void gemm_ab32_bt(const float* __restrict__ A,
        const float* __restrict__ B, unsigned short* __restrict__ CT, int M, int N, int K) {
    __shared__ float As[32][33];
    __shared__ float Bs[32][33];
    int tid = threadIdx.x, tx = tid & 15, ty = tid >> 4;
    int m0 = blockIdx.y * 32, n0 = blockIdx.x * 32;
    float acc[2][2] = {};
    for (int k0 = 0; k0 < K; k0 += 32) {
        #pragma unroll
        for (int l = 0; l < 4; ++l) {
            int idx = tid + 256 * l;
            int r = idx >> 5, c = idx & 31;
            As[r][c] = A[(size_t)(m0 + r) * K + k0 + c];
            Bs[r][c] = B[(size_t)(k0 + r) * N + n0 + c];
        }
        __syncthreads();
        #pragma unroll
        for (int kk = 0; kk < 32; ++kk) {
            float a0 = As[ty * 2][kk], a1 = As[ty * 2 + 1][kk];
            float b0 = Bs[kk][tx * 2], b1 = Bs[kk][tx * 2 + 1];
            acc[0][0] += a0 * b0; acc[0][1] += a0 * b1;
            acc[1][0] += a1 * b0; acc[1][1] += a1 * b1;
        }
        __syncthreads();
    }
    // stage C tile in LDS (reuse As), write transposed bf16 coalesced
    #pragma unroll
    for (int i = 0; i < 2; ++i)
        #pragma unroll
        for (int j = 0; j < 2; ++j)
            As[ty * 2 + i][tx * 2 + j] = acc[i][j];   // As[m_local][n_local]
    __syncthreads();
    int nl = tid >> 3, moff = (tid & 7) * 4;
    ushort4 o;
    o.x = f2bf(As[moff + 0][nl]);
    o.y = f2bf(As[moff + 1][nl]);
    o.z = f2bf(As[moff + 2][nl]);
    o.w = f2bf(As[moff + 3][nl]);
    *(ushort4*)(CT + (size_t)(n0 + nl) * M + m0 + moff) = o;
}

// 32x32 tile, C = A^T@B with A[K][M], B[K][N]; optional sumsq-only mode
__global__ __launch_bounds__(256) void gemm_atb32(const float* __restrict__ A, const float* __restrict__ B,
        float* __restrict__ C, int M, int N, int K,
        const float* __restrict__ bias, int relu, float* sumsq_acc) {
    __shared__ float As[32][33];
    __shared__ float Bs[32][33];
    __shared__ float red[256];
    int tid = threadIdx.x, tx = tid & 15, ty = tid >> 4;
    int m0 = blockIdx.y * 32, n0 = blockIdx.x * 32;
    float acc[2][2] = {};
    for (int k0 = 0; k0 < K; k0 += 32) {
        #pragma unroll
        for (int l = 0; l < 4; ++l) {
            int idx = tid + 256 * l;
            int r = idx >> 5, c = idx & 31;
            As[c][r] = A[(size_t)(k0 + r) * M + m0 + c];
            Bs[r][c] = B[(size_t)(k0 + r) * N + n0 + c];
        }
        __syncthreads();
        #pragma unroll
        for (int kk = 0; kk < 32; ++kk) {
            float a0 = As[ty * 2][kk], a1 = As[ty * 2 + 1][kk];
            float b0 = Bs[kk][tx * 2], b1 = Bs[kk][tx * 2 + 1];
            acc[0][0] += a0 * b0; acc[0][1] += a0 * b1;
            acc[1][0] += a1 * b0; acc[1][1] += a1 * b1;
        }
        __syncthreads();
    }
    if (sumsq_acc) {
        float ss = acc[0][0] * acc[0][0] + acc[0][1] * acc[0][1]
                 + acc[1][0] * acc[1][0] + acc[1][1] * acc[1][1];
        red[tid] = ss; __syncthreads();
        for (int s = 128; s > 0; s >>= 1) { if (tid < s) red[tid] += red[tid + s]; __syncthreads(); }
        if (tid == 0) atomicAdd(sumsq_acc, red[0]);
        return;
    }
    #pragma unroll
    for (int i = 0; i < 2; ++i)
        #pragma unroll
        for (int j = 0; j < 2; ++j) {
            int m = m0 + ty * 2 + i, n = n0 + tx * 2 + j;
            float v = acc[i][j];
            if (bias) v += bias[n];
            if (relu) v = fmaxf(v, 0.f);
            C[(size_t)m * N + n] = v;
        }
}

// C[M][16] (+)= A[M][K] @ B[K][16]
__global__ __launch_bounds__(256) void k_gemm_n16(const float* __restrict__ A, const float* __restrict__ B,
        float* __restrict__ C, int M, int K, int accum) {
    __shared__ float As[16][64];
    __shared__ float Bs[64][16];
    int tid = threadIdx.x;
    int r = tid >> 4, c = tid & 15;
    int m0 = blockIdx.x * 16;
    float acc = 0.f;
    for (int k0 = 0; k0 < K; k0 += 64) {
        #pragma unroll
        for (int l = 0; l < 4; ++l) {
            int idx = tid + 256 * l;
            int rr = idx >> 6, cc = idx & 63;
            As[rr][cc] = A[(size_t)(m0 + rr) * K + k0 + cc];
            int kk = idx >> 4, c2 = idx & 15;
            Bs[kk][c2] = B[(size_t)(k0 + kk) * 16 + c2];
        }
        __syncthreads();
        #pragma unroll 16
        for (int kk = 0; kk < 64; ++kk) acc += As[r][kk] * Bs[kk][c];
        __syncthreads();
    }
    float* p = &C[(size_t)(m0 + r) * 16 + c];
    if (accum) acc += *p;
    *p = acc;
}

// =========================== bf16 MFMA GEMMs ===========================

// split-K partial store: P[z][M][N] = partial of sum_k A[m][k]*B[n][k]
__global__ __launch_bounds__(256) void gemm_tn_bf16_part(
        const unsigned short* __restrict__ A, const unsigned short* __restrict__ B,
        float* __restrict__ P, int M, int N, int K) {
    __shared__ __align__(16) unsigned short As[128 * 64];
    __shared__ __align__(16) unsigned short Bs[128 * 64];
    int tid = threadIdx.x;
    int wave = tid >> 6, lane = tid & 63;
    int wm = wave >> 1, wn = wave & 1;
    int m0 = blockIdx.x * 128, n0 = blockIdx.y * 128;
    int kchunk = K / gridDim.z;
    int k0 = blockIdx.z * kchunk;
    float* Pz = P + (size_t)blockIdx.z * M * N;
    floatx4 acc[4][4] = {};
    int sr = tid >> 3;
    int sc = (tid & 7) * 8;
    int q = lane >> 4, lm = lane & 15;
    for (int kt = 0; kt < kchunk; kt += 64) {
        #pragma unroll
        for (int p = 0; p < 4; ++p) {
            int mrow = sr + p * 32;
            int gk = k0 + kt + sc;
            int scs = sc ^ ((mrow & 7) * 8);
            *(short8*)(&As[mrow * 64 + scs]) = *(const short8*)(&A[(size_t)(m0 + mrow) * K + gk]);
            *(short8*)(&Bs[mrow * 64 + scs]) = *(const short8*)(&B[(size_t)(n0 + mrow) * K + gk]);
        }
        __syncthreads();
        #pragma unroll
        for (int ks = 0; ks < 64; ks += 32) {
            short8 af[4], bf[4];
            int kk = ks + q * 8;
            #pragma unroll
            for (int i = 0; i < 4; ++i) {
                int ml = wm * 64 + i * 16 + lm;
                af[i] = *(const short8*)(&As[ml * 64 + (kk ^ ((ml & 7) * 8))]);
                int nl = wn * 64 + i * 16 + lm;
                bf[i] = *(const short8*)(&Bs[nl * 64 + (kk ^ ((nl & 7) * 8))]);
            }
            #pragma unroll
            for (int i = 0; i < 4; ++i)
                #pragma unroll
                for (int j = 0; j < 4; ++j)
                    acc[i][j] = __builtin_amdgcn_mfma_f32_16x16x32_bf16(af[i], bf[j], acc[i][j], 0, 0, 0);
        }
        __syncthreads();
    }
    for (int i = 0; i < 4; ++i) {
        int rowb = m0 + wm * 64 + i * 16 + q * 4;
        for (int j = 0; j < 4; ++j) {
            int col = n0 + wn * 64 + j * 16 + lm;
            #pragma unroll
            for (int r = 0; r < 4; ++r)
                Pz[(size_t)(rowb + r) * N + col] = acc[i][j][r];
        }
    }
}

// full-K store with bias+relu (s1o)
__global__ __launch_bounds__(256) void gemm_tn_bf16_store(
        const unsigned short* __restrict__ A, const unsigned short* __restrict__ B,
        float* __restrict__ C, int M, int N, int K,
        const float* __restrict__ bias, int relu) {
    __shared__ __align__(16) unsigned short As[128 * 64];
    __shared__ __align__(16) unsigned short Bs[128 * 64];
    int tid = threadIdx.x;
    int wave = tid >> 6, lane = tid & 63;
    int wm = wave >> 1, wn = wave & 1;
    int m0 = blockIdx.x * 128, n0 = blockIdx.y * 128;
    floatx4 acc[4][4] = {};
    int sr = tid >> 3;
    int sc = (tid & 7) * 8;
    int q = lane >> 4, lm = lane & 15;
    for (int kt = 0; kt < K; kt += 64) {
        #pragma unroll
        for (int p = 0; p < 4; ++p) {
            int mrow = sr + p * 32;
            int gk = kt + sc;
            int scs = sc ^ ((mrow & 7) * 8);
            *(short8*)(&As[mrow * 64 + scs]) = *(const short8*)(&A[(size_t)(m0 + mrow) * K + gk]);
            *(short8*)(&Bs[mrow * 64 + scs]) = *(const short8*)(&B[(size_t)(n0 + mrow) * K + gk]);
        }
        __syncthreads();
        #pragma unroll
        for (int ks = 0; ks < 64; ks += 32) {
            short8 af[4], bf[4];
            int kk = ks + q * 8;
            #pragma unroll
            for (int i = 0; i < 4; ++i) {
                int ml = wm * 64 + i * 16 + lm;
                af[i] = *(const short8*)(&As[ml * 64 + (kk ^ ((ml & 7) * 8))]);
                int nl = wn * 64 + i * 16 + lm;
                bf[i] = *(const short8*)(&Bs[nl * 64 + (kk ^ ((nl & 7) * 8))]);
            }
            #pragma unroll
            for (int i = 0; i < 4; ++i)
                #pragma unroll
                for (int j = 0; j < 4; ++j)
                    acc[i][j] = __builtin_amdgcn_mfma_f32_16x16x32_bf16(af[i], bf[j], acc[i][j], 0, 0, 0);
        }
        __syncthreads();
    }
    for (int i = 0; i < 4; ++i) {
        int rowb = m0 + wm * 64 + i * 16 + q * 4;
        for (int j = 0; j < 4; ++j) {
            int col = n0 + wn * 64 + j * 16 + lm;
            float bv = bias ? bias[col] : 0.f;
            #pragma unroll
            for (int r = 0; r < 4; ++r) {
                float v = acc[i][j][r] + bv;
                if (relu) v = fmaxf(v, 0.f);
                C[(size_t)(rowb + r) * N + col] = v;
            }
        }
    }
}

// reduce nsplit partials; optional fp32 C, dual bf16 Cb, sumsq accumulation
__global__ __launch_bounds__(256) void k_reduce4(const float* __restrict__ P,
        float* __restrict__ C, unsigned short* __restrict__ Cb,
        int n, int nsplit, float* ss_acc) {
    __shared__ float red[256];
    float ss = 0.f;
    for (int i4 = (blockIdx.x * 256 + threadIdx.x) * 4; i4 < n; i4 += gridDim.x * 256 * 4) {
        float4 v = *(const float4*)(P + i4);
        for (int s = 1; s < nsplit; ++s) {
            float4 w = *(const float4*)(P + (size_t)s * n + i4);
            v.x += w.x; v.y += w.y; v.z += w.z; v.w += w.w;
        }
        if (C) *(float4*)(C + i4) = v;
        if (Cb) {
            ushort4 o; o.x = f2bf(v.x); o.y = f2bf(v.y); o.z = f2bf(v.z); o.w = f2bf(v.w);
            *(ushort4*)(Cb + i4) = o;
        }
        ss += v.x * v.x + v.y * v.y + v.z * v.z + v.w * v.w;
    }
    if (!ss_acc) return;
    red[threadIdx.x] = ss; __syncthreads();
    for (int s = 128; s > 0; s >>= 1) { if (threadIdx.x < s) red[threadIdx.x] += red[threadIdx.x + s]; __syncthreads(); }
    if (threadIdx.x == 0) atomicAdd(ss_acc, red[0]);
}

// reduce nsplit partials [ns][M][N] -> C fp32 with bias (len N) + relu
__global__ __launch_bounds__(256) void k_reduce_br(const float* __restrict__ P,
        float* __restrict__ C, int n, int N, int nsplit,
        const float* __restrict__ bias, int relu) {
    for (int i4 = (blockIdx.x * 256 + threadIdx.x) * 4; i4 < n; i4 += gridDim.x * 256 * 4) {
        float4 v = *(const float4*)(P + i4);
        for (int s = 1; s < nsplit; ++s) {
            float4 w = *(const float4*)(P + (size_t)s * n + i4);
            v.x += w.x; v.y += w.y; v.z += w.z; v.w += w.w;
        }
        if (bias) {
            float4 b = *(const float4*)(bias + (i4 % N));
            v.x += b.x; v.y += b.y; v.z += b.z; v.w += b.w;
        }
        if (relu) {
            v.x = fmaxf(v.x, 0.f); v.y = fmaxf(v.y, 0.f);
            v.z = fmaxf(v.z, 0.f); v.w = fmaxf(v.w, 0.f);
        }
        *(float4*)(C + i4) = v;
    }
}

// =========================== transposes ===========================

__global__ __launch_bounds__(256) void k_transpose_f2b(
        const float* __restrict__ in, unsigned short* __restrict__ outb,
        int R, int C, const float* __restrict__ rowscale) {
    __shared__ float tile[64][65];
    int rb = blockIdx.y * 64, cb = blockIdx.x * 64;
    int t = threadIdx.x;
    int lr = t >> 4, lc4 = (t & 15) * 4;
    #pragma unroll
    for (int p = 0; p < 4; ++p) {
        int r = rb + lr + p * 16;
        float4 v = *(const float4*)(in + (size_t)r * C + cb + lc4);
        float s = rowscale ? rowscale[r] : 1.0f;
        tile[lr + p * 16][lc4 + 0] = v.x * s;
        tile[lr + p * 16][lc4 + 1] = v.y * s;
        tile[lr + p * 16][lc4 + 2] = v.z * s;
        tile[lr + p * 16][lc4 + 3] = v.w * s;
    }
    __syncthreads();
    int cc0 = t >> 5, rr = (t & 31) * 2;
    #pragma unroll
    for (int p = 0; p < 8; ++p) {
        int cc = cc0 + p * 8;
        unsigned a = f2bf(tile[rr][cc]);
        unsigned b = f2bf(tile[rr + 1][cc]);
        *(unsigned*)(outb + (size_t)(cb + cc) * R + rb + rr) = a | (b << 16);
    }
}

__global__ __launch_bounds__(256) void k_transpose_b2b(
        const unsigned short* __restrict__ in, unsigned short* __restrict__ out, int R, int C) {
    __shared__ __align__(16) unsigned short tile[64][72];
    int rb = blockIdx.y * 64, cb = blockIdx.x * 64;
    int t = threadIdx.x;
    int lr = t >> 3, lc = (t & 7) * 8;
    #pragma unroll
    for (int p = 0; p < 2; ++p) {
        int r = lr + p * 32;
        *(short8*)(&tile[r][lc]) = *(const short8*)(&in[(size_t)(rb + r) * C + cb + lc]);
    }
    __syncthreads();
    int cc0 = t >> 4, rr = (t & 15) * 4;
    #pragma unroll
    for (int p = 0; p < 4; ++p) {
        int cc = cc0 + p * 16;
        unsigned long long v = (unsigned long long)tile[rr][cc]
                             | ((unsigned long long)tile[rr + 1][cc] << 16)
                             | ((unsigned long long)tile[rr + 2][cc] << 32)
                             | ((unsigned long long)tile[rr + 3][cc] << 48);
        *(unsigned long long*)(&out[(size_t)(cb + cc) * R + rb + rr]) = v;
    }
}

// an1Tb[j][i] = bf16( dinv[i]*(adj1[i][j] + (i==j)*dfix[i])*dinv[j] )
__global__ __launch_bounds__(256) void k_anorm_tb(const float* __restrict__ adjm, int n,
        const float* __restrict__ dinvv, const float* __restrict__ dfix,
        unsigned short* __restrict__ outb) {
    __shared__ float tile[64][65];
    int rb = blockIdx.y * 64, cb = blockIdx.x * 64;
    int t = threadIdx.x;
    int lr = t >> 4, lc4 = (t & 15) * 4;
    #pragma unroll
    for (int p = 0; p < 4; ++p) {
        int i = rb + lr + p * 16;
        float4 v = *(const float4*)(adjm + (size_t)i * n + cb + lc4);
        float di = dinvv[i];
        float vv[4] = {v.x, v.y, v.z, v.w};
        #pragma unroll
        for (int q = 0; q < 4; ++q) {
            int j = cb + lc4 + q;
            float val = vv[q];
            if (i == j) val += dfix[i];
            tile[lr + p * 16][lc4 + q] = di * val * dinvv[j];
        }
    }
    __syncthreads();
    int cc0 = t >> 5, rr = (t & 31) * 2;
    #pragma unroll
    for (int p = 0; p < 8; ++p) {
        int cc = cc0 + p * 8;
        unsigned a = f2bf(tile[rr][cc]);
        unsigned b = f2bf(tile[rr + 1][cc]);
        *(unsigned*)(outb + (size_t)(cb + cc) * n + rb + rr) = a | (b << 16);
    }
}

// =========================== aggregation / misc ===========================

__global__ __launch_bounds__(64) void k_agg_b16(const unsigned short* __restrict__ h,
        float* __restrict__ out, unsigned short* __restrict__ outb,
        const int* __restrict__ cptr, const int* __restrict__ colr,
        const float* __restrict__ coln, const float* __restrict__ dinv,
        const float* __restrict__ bias, int relu) {
    int c = blockIdx.x, t = threadIdx.x;
    int f0 = t * 2;
    float d = dinv[c], dd = d * d;
    unsigned u = *(const unsigned*)(h + (size_t)c * 128 + f0);
    float a0 = dd * bf2f((unsigned short)(u & 0xffff));
    float a1 = dd * bf2f((unsigned short)(u >> 16));
    int e0 = cptr[c], e1 = cptr[c + 1];
    for (int e = e0; e < e1; ++e) {
        float w = coln[e];
        unsigned v = *(const unsigned*)(h + (size_t)colr[e] * 128 + f0);
        a0 += w * bf2f((unsigned short)(v & 0xffff));
        a1 += w * bf2f((unsigned short)(v >> 16));
    }
    if (bias) { a0 += bias[f0]; a1 += bias[f0 + 1]; }
    if (relu) { a0 = fmaxf(a0, 0.f); a1 = fmaxf(a1, 0.f); }
    if (out) { out[(size_t)c * 128 + f0] = a0; out[(size_t)c * 128 + f0 + 1] = a1; }
    if (outb) {
        unsigned o = (unsigned)f2bf(a0) | ((unsigned)f2bf(a1) << 16);
        *(unsigned*)(outb + (size_t)c * 128 + f0) = o;
    }
}

// F=16 agg + fused log_softmax (16-lane groups), writes prediction directly
__global__ __launch_bounds__(256) void k_agg16_ls(const float* __restrict__ h, float* __restrict__ pred,
        const int* __restrict__ cptr, const int* __restrict__ colr,
        const float* __restrict__ coln, const float* __restrict__ dinv,
        const float* __restrict__ bias) {
    int node = blockIdx.x * 16 + (threadIdx.x >> 4);
    int f = threadIdx.x & 15;
    float d = dinv[node];
    float acc = d * d * h[(size_t)node * 16 + f];
    int e0 = cptr[node], e1 = cptr[node + 1];
    for (int e = e0; e < e1; ++e)
        acc += coln[e] * h[(size_t)colr[e] * 16 + f];
    acc += bias[f];
    acc = fmaxf(acc, 0.f);
    float m = acc;
    #pragma unroll
    for (int off = 1; off < 16; off <<= 1) m = fmaxf(m, __shfl_xor(m, off, 16));
    float ex = expf(acc - m);
    float s = ex;
    #pragma unroll
    for (int off = 1; off < 16; off <<= 1) s += __shfl_xor(s, off, 16);
    pred[(size_t)node * 16 + f] = acc - m - logf(s);
}

__global__ __launch_bounds__(256) void k_softmax1024(const float* __restrict__ x,
        unsigned short* __restrict__ Sb, const float* __restrict__ mask, float* ent_acc) {
    __shared__ float red[256];
    int r = blockIdx.x, tid = threadIdx.x;
    const float* xr = x + (size_t)r * 1024;
    float4 v = *(const float4*)(xr + tid * 4);
    float m = fmaxf(fmaxf(v.x, v.y), fmaxf(v.z, v.w));
    red[tid] = m; __syncthreads();
    for (int s = 128; s > 0; s >>= 1) { if (tid < s) red[tid] = fmaxf(red[tid], red[tid + s]); __syncthreads(); }
    m = red[0]; __syncthreads();
    float e0 = expf(v.x - m), e1 = expf(v.y - m), e2 = expf(v.z - m), e3 = expf(v.w - m);
    red[tid] = e0 + e1 + e2 + e3; __syncthreads();
    for (int s = 128; s > 0; s >>= 1) { if (tid < s) red[tid] += red[tid + s]; __syncthreads(); }
    float inv = 1.0f / red[0]; __syncthreads();
    float mk = mask ? mask[r] : 1.0f;
    float s0 = e0 * inv * mk, s1 = e1 * inv * mk, s2 = e2 * inv * mk, s3 = e3 * inv * mk;
    float ent = -(s0 * logf(s0 + 1e-15f) + s1 * logf(s1 + 1e-15f)
                + s2 * logf(s2 + 1e-15f) + s3 * logf(s3 + 1e-15f));
    ushort4 o;
    o.x = f2bf(s0); o.y = f2bf(s1); o.z = f2bf(s2); o.w = f2bf(s3);
    *(ushort4*)(Sb + (size_t)r * 1024 + tid * 4) = o;
    red[tid] = ent; __syncthreads();
    for (int s = 128; s > 0; s >>= 1) { if (tid < s) red[tid] += red[tid + s]; __syncthreads(); }
    if (tid == 0) atomicAdd(ent_acc, red[0]);
}

__global__ __launch_bounds__(256) void k_softmax_ent(const float* __restrict__ x, float* __restrict__ S,
        int W, const float* __restrict__ mask, float* ent_acc) {
    __shared__ float red[256];
    int row = blockIdx.x, tid = threadIdx.x;
    const float* xr = x + (size_t)row * W;
    float m = -3.0e38f;
    for (int q = tid; q < W; q += 256) m = fmaxf(m, xr[q]);
    red[tid] = m; __syncthreads();
    for (int s = 128; s > 0; s >>= 1) { if (tid < s) red[tid] = fmaxf(red[tid], red[tid + s]); __syncthreads(); }
    m = red[0]; __syncthreads();
    float sum = 0.f;
    for (int q = tid; q < W; q += 256) sum += expf(xr[q] - m);
    red[tid] = sum; __syncthreads();
    for (int s = 128; s > 0; s >>= 1) { if (tid < s) red[tid] += red[tid + s]; __syncthreads(); }
    float inv = 1.0f / red[0]; __syncthreads();
    float mk = mask ? mask[row] : 1.0f;
    float* Sr = S + (size_t)row * W;
    float ent = 0.f;
    for (int q = tid; q < W; q += 256) {
        float v = expf(xr[q] - m) * inv * mk;
        Sr[q] = v;
        ent -= v * logf(v + 1e-15f);
    }
    red[tid] = ent; __syncthreads();
    for (int s = 128; s > 0; s >>= 1) { if (tid < s) red[tid] += red[tid + s]; __syncthreads(); }
    if (tid == 0) atomicAdd(ent_acc, red[0]);
}

// L2-segmented SpMM, 4 waves/block = 4 rows, pass p = cols [p*128, p*128+128)
__global__ __launch_bounds__(256) void k_spmm_seg(const unsigned short* __restrict__ Sb,
        const int* __restrict__ rptr, const int* __restrict__ rowc, const float* __restrict__ roww,
        unsigned short* __restrict__ tb) {
    int wave = threadIdx.x >> 6, lane = threadIdx.x & 63;
    int r = blockIdx.x * 4 + wave;
    int j0 = blockIdx.y * 128 + lane * 2;
    float a0 = 0.f, a1 = 0.f;
    int e0 = rptr[r], e1 = rptr[r + 1];
    for (int e = e0; e < e1; ++e) {
        int c = rowc[e]; float w = roww[e];
        unsigned v = *(const unsigned*)(Sb + (size_t)c * 1024 + j0);
        a0 += w * bf2f((unsigned short)(v & 0xffff));
        a1 += w * bf2f((unsigned short)(v >> 16));
    }
    unsigned o = (unsigned)f2bf(a0) | ((unsigned)f2bf(a1) << 16);
    *(unsigned*)(tb + (size_t)r * 1024 + j0) = o;
}

__global__ void k_colsum_part(const float* __restrict__ adjm, int n, float* part) {
    int j = blockIdx.x * blockDim.x + threadIdx.x;
    if (j >= n) return;
    int r0 = blockIdx.y * 64;
    float s = 0.f;
    for (int r = r0; r < r0 + 64; ++r) s += adjm[(size_t)r * n + j];
    part[(size_t)blockIdx.y * n + j] = s;
}

// dfix + dinv for adj1 + cross = trace(adj1)
__global__ void k_dfix_part(const float* __restrict__ adjm, int n, const float* __restrict__ part,
                            int nparts, float* dinvv, float* dfix, float* cross_acc) {
    __shared__ float red[256];
    int j = blockIdx.x * blockDim.x + threadIdx.x;
    float diag = 0.f;
    if (j < n) {
        float s = 0.f;
        for (int p = 0; p < nparts; ++p) s += part[(size_t)p * n + j];
        diag = adjm[(size_t)j * n + j];
        float fix = (diag == 0.f) ? 1.0f : 0.f;
        s += fix;
        dfix[j] = fix;
        dinvv[j] = (s > 0.f) ? 1.0f / sqrtf(s) : 0.f;
    }
    red[threadIdx.x] = diag; __syncthreads();
    for (int s = 128; s > 0; s >>= 1) { if (threadIdx.x < s) red[threadIdx.x] += red[threadIdx.x + s]; __syncthreads(); }
    if (threadIdx.x == 0) atomicAdd(cross_acc, red[0]);
}

// fused colsum+dfix for n=128 + cross2 = trace(adj2)
__global__ __launch_bounds__(128) void k_coldfix128(const float* __restrict__ adjm,
        float* dinvv, float* dfix, float* cross2_out) {
    __shared__ float red[128];
    int j = threadIdx.x;
    float s = 0.f;
    for (int i = 0; i < 128; ++i) s += adjm[(size_t)i * 128 + j];
    float diag = adjm[(size_t)j * 128 + j];
    float fix = (diag == 0.f) ? 1.0f : 0.f;
    s += fix;
    dfix[j] = fix;
    dinvv[j] = (s > 0.f) ? 1.0f / sqrtf(s) : 0.f;
    red[j] = diag; __syncthreads();
    for (int st = 64; st > 0; st >>= 1) { if (j < st) red[j] += red[j + st]; __syncthreads(); }
    if (j == 0) *cross2_out = red[0];
}

__global__ void k_anorm(const float* __restrict__ adjm, int n, const float* __restrict__ dinvv,
                        const float* __restrict__ dfix, float* __restrict__ anorm) {
    int idx = blockIdx.x * 256 + threadIdx.x;
    if (idx >= n * n) return;
    int i = idx / n, j = idx % n;
    float v = adjm[idx] + ((i == j) ? dfix[j] : 0.f);
    anorm[idx] = dinvv[i] * v * dinvv[j];
}

__global__ void k_finalize(const float* __restrict__ sc, float* loss) {
    if (threadIdx.x == 0 && blockIdx.x == 0) {
        float e1     = sc[0] / 8192.0f;
        float cross  = sc[1];
        float g2     = sc[2];
        float sumA2  = sc[3];
        float ssadj1 = sc[4];
        float e2     = sc[5] / 1024.0f;
        float cross2 = sc[6];
        float g2b    = sc[7];
        float l1 = sqrtf(fmaxf(sumA2 - 2.0f * cross + g2, 0.f)) / 67108864.0f;
        float l2 = sqrtf(fmaxf(ssadj1 - 2.0f * cross2 + g2b, 0.f)) / 1048576.0f;
        *loss = l1 + e1 + l2 + e2;
    }
}

// =========================== launcher ===========================

extern "C" void kernel_launch(void* const* d_in, const int* in_sizes, int n_in,
                              void* d_out, int out_size, void* d_ws, size_t ws_size,
                              hipStream_t stream) {
    const int N = N_NODES, E = N_EDGES;
    const float* x0     = (const float*)d_in[0];
    const int*   eidx   = (const int*)d_in[1];
    const float* ew     = (const float*)d_in[2];
    const float* mask   = (const float*)d_in[4];
    const float* W0_in  = (const float*)d_in[5];
    const float* b0_in  = (const float*)d_in[6];
    const float* Wp1    = (const float*)d_in[7];
    const float* bp1    = (const float*)d_in[8];
    const float* W1_in  = (const float*)d_in[9];
    const float* b1_in  = (const float*)d_in[10];
    const float* Wp2    = (const float*)d_in[11];
    const float* bp2    = (const float*)d_in[12];
    const float* W2_in  = (const float*)d_in[13];
    const float* b2_in  = (const float*)d_in[14];
    const float* W1_out = (const float*)d_in[15];
    const float* b1_out = (const float*)d_in[16];
    const float* W0_out = (const float*)d_in[17];
    const float* b0_out = (const float*)d_in[18];

    float* out   = (float*)d_out;
    float* predo = out + OUT_PRED;
    float* s1o   = out + OUT_S1;
    float* losso = out + OUT_LOSS;
    float* adj1o = out + OUT_ADJ1;

    float* wsf = (float*)d_ws;
    int*   wsi = (int*)d_ws;
    float* deg   = wsf + OFF_DEG;
    int*   cntc  = wsi + OFF_CNTC;
    int*   cntr  = wsi + OFF_CNTR;
    float* scal  = wsf + OFF_SCAL;
    int*   cptr  = wsi + OFF_COLPTR;
    int*   rptr  = wsi + OFF_ROWPTR;
    int*   curc  = wsi + OFF_CURC;
    int*   curr  = wsi + OFF_CURR;
    int*   colr  = wsi + OFF_COLR;
    float* coln  = wsf + OFF_COLN;
    int*   rowc  = wsi + OFF_ROWC;
    float* roww  = wsf + OFF_ROWW;
    float* dinv  = wsf + OFF_DINV;
    float* x0_   = wsf + OFF_X0;
    unsigned short* h0b   = (unsigned short*)(wsf + OFF_H0);
    unsigned short* Sb    = (unsigned short*)(wsf + OFF_S);
    unsigned short* TT    = (unsigned short*)(wsf + OFF_TT);
    unsigned short* AN1TB = (unsigned short*)(wsf + OFF_AN1TB);
    unsigned short* ADJ1B = (unsigned short*)(wsf + OFF_ADJ1B);
    unsigned short* HAT   = (unsigned short*)(wsf + OFF_HAT);
    unsigned short* HBT   = (unsigned short*)(wsf + OFF_HBT);
    unsigned short* HCATT = (unsigned short*)(wsf + OFF_HCATT);
    unsigned short* S2ST  = (unsigned short*)(wsf + OFF_S2ST);
    unsigned short* ST    = (unsigned short*)(wsf + OFF_ST);
    unsigned short* TBF   = (unsigned short*)(wsf + OFF_TBF);
    unsigned short* WP1T  = (unsigned short*)(wsf + OFF_WP1T);
    unsigned short* X0T   = (unsigned short*)(wsf + OFF_X0T);
    unsigned short* x0b   = (unsigned short*)(wsf + OFF_X0B);
    float* PADJ  = wsf + OFF_PADJ;
    float* PG    = wsf + OFF_PG;
    float* PP    = wsf + OFF_PP;
    float* PX1   = wsf + OFF_PX1;
    float* x1    = wsf + OFF_X1;
    float* y16   = wsf + OFF_Y16;
    float* x1_   = wsf + OFF_X1_;
    float* s2    = wsf + OFF_S2;
    float* S2s   = wsf + OFF_S2S;
    float* u     = wsf + OFF_U;
    float* x2    = wsf + OFF_X2;
    float* adj2  = wsf + OFF_ADJ2;
    float* hC    = wsf + OFF_HC;
    float* x2_   = wsf + OFF_X2_;
    float* an2   = wsf + OFF_AN2;
    float* z2    = wsf + OFF_Z2;
    float* hcat  = wsf + OFF_HCAT;
    float* x1o_  = wsf + OFF_X1O;
    float* p16   = wsf + OFF_P16;
    float* di1   = wsf + OFF_DI1;
    float* df1   = wsf + OFF_DF1;
    float* di2   = wsf + OFF_DI2;
    float* df2   = wsf + OFF_DF2;
    float* cspart = wsf + OFF_CURC;

    const int* row = eidx;
    const int* col = eidx + E;

    hipMemsetAsync(wsf, 0, (size_t)ZERO_FLOATS * sizeof(float), stream);

    // --- graph structure ---
    k_hist<<<E / 256, 256, 0, stream>>>(row, col, ew, E, deg, cntc, cntr, &scal[3]);
    k_scan<<<1, 1024, 0, stream>>>(cntc, cntr, cptr, rptr, curc, curr, N, E, deg, dinv);
    k_scatter<<<E / 256, 256, 0, stream>>>(row, col, ew, E, dinv, curc, curr, colr, coln, rowc, roww);

    // --- level 0 GCN ---
    gemm_ab_b16<<<dim3(2, 128), 256, 0, stream>>>(x0, W0_in, h0b, 8192, 128, 128);
    k_agg_b16<<<N, 64, 0, stream>>>(h0b, x0_, x0b, cptr, colr, coln, dinv, b0_in, 1);

    // --- s1 = relu((M^T x0_)@Wp1 + bp1) ---
    k_agg_b16<<<N, 64, 0, stream>>>(x0b, nullptr, h0b, cptr, colr, coln, dinv, nullptr, 0);
    k_transpose_f2b<<<dim3(16, 2), 256, 0, stream>>>(Wp1, WP1T, 128, 1024, nullptr);
    gemm_tn_bf16_store<<<dim3(64, 8), 256, 0, stream>>>(h0b, WP1T, s1o, 8192, 1024, 128, bp1, 1);

    // --- diff_pool level 1 ---
    k_softmax1024<<<N, 256, 0, stream>>>(s1o, Sb, mask, &scal[0]);
    k_spmm_seg<<<dim3(N / 4, 8), 256, 0, stream>>>(Sb, rptr, rowc, roww, TBF);
    k_transpose_b2b<<<dim3(16, 128), 256, 0, stream>>>(Sb, ST, 8192, 1024);
    k_transpose_b2b<<<dim3(16, 128), 256, 0, stream>>>(TBF, TT, 8192, 1024);
    k_transpose_f2b<<<dim3(2, 128), 256, 0, stream>>>(x0_, X0T, 8192, 128, mask);

    gemm_tn_bf16_part<<<dim3(8, 8, 4), 256, 0, stream>>>(ST, TT, PADJ, 1024, 1024, 8192);
    gemm_tn_bf16_part<<<dim3(8, 8, 4), 256, 0, stream>>>(ST, ST, PG, 1024, 1024, 8192);
    gemm_tn_bf16_part<<<dim3(8, 1, 16), 256, 0, stream>>>(ST, X0T, PX1, 1024, 128, 8192);
    k_reduce4<<<1024, 256, 0, stream>>>(PADJ, adj1o, ADJ1B, 1024 * 1024, 4, &scal[4]);
    k_reduce4<<<1024, 256, 0, stream>>>(PG, nullptr, nullptr, 1024 * 1024, 4, &scal[2]);
    k_reduce4<<<128, 256, 0, stream>>>(PX1, x1, nullptr, 1024 * 128, 16, nullptr);

    // --- a_norm for adj1 (bf16 transposed only) + cross = tr(adj1) ---
    k_colsum_part<<<dim3(4, 16), 256, 0, stream>>>(adj1o, 1024, cspart);
    k_dfix_part<<<4, 256, 0, stream>>>(adj1o, 1024, cspart, 16, di1, df1, &scal[1]);
    k_anorm_tb<<<dim3(16, 16), 256, 0, stream>>>(adj1o, 1024, di1, df1, AN1TB);

    // --- level 1 dense GCNs (MFMA, K=1024) ---
    gemm_ab32_bt<<<dim3(4, 32), 256, 0, stream>>>(x1, W1_in, HAT, 1024, 128, 128);
    gemm_tn_bf16_part<<<dim3(8, 1, 8), 256, 0, stream>>>(AN1TB, HAT, PP, 1024, 128, 1024);
    k_reduce_br<<<128, 256, 0, stream>>>(PP, x1_, 1024 * 128, 128, 8, b1_in, 1);
    gemm_ab32_bt<<<dim3(4, 32), 256, 0, stream>>>(x1_, Wp2, HBT, 1024, 128, 128);
    gemm_tn_bf16_part<<<dim3(8, 1, 8), 256, 0, stream>>>(AN1TB, HBT, PP, 1024, 128, 1024);
    k_reduce_br<<<128, 256, 0, stream>>>(PP, s2, 1024 * 128, 128, 8, bp2, 1);

    // --- diff_pool level 2 ---
    k_softmax_ent<<<1024, 256, 0, stream>>>(s2, S2s, 128, nullptr, &scal[5]);
    k_transpose_f2b<<<dim3(2, 16), 256, 0, stream>>>(S2s, S2ST, 1024, 128, nullptr);
    gemm_tn_bf16_part<<<dim3(8, 1, 8), 256, 0, stream>>>(ADJ1B, S2ST, PP, 1024, 128, 1024);
    k_reduce_br<<<128, 256, 0, stream>>>(PP, u, 1024 * 128, 128, 8, nullptr, 0);
    gemm_atb32<<<dim3(4, 4), 256, 0, stream>>>(S2s, x1_, x2, 128, 128, 1024, nullptr, 0, nullptr);
    gemm_atb32<<<dim3(4, 4), 256, 0, stream>>>(S2s, u, adj2, 128, 128, 1024, nullptr, 0, nullptr);
    gemm_atb32<<<dim3(4, 4), 256, 0, stream>>>(S2s, S2s, nullptr, 128, 128, 1024, nullptr, 0, &scal[7]);

    // --- a_norm for adj2 (+cross2 = tr(adj2)), level 2 GCN ---
    k_coldfix128<<<1, 128, 0, stream>>>(adj2, di2, df2, &scal[6]);
    k_anorm<<<64, 256, 0, stream>>>(adj2, 128, di2, df2, an2);
    gemm_ab32<<<dim3(4, 4), 256, 0, stream>>>(x2, W2_in, hC, 128, 128, 128, nullptr, 0, 0);
    gemm_atb32<<<dim3(4, 4), 256, 0, stream>>>(an2, hC, x2_, 128, 128, 128, b2_in, 1, nullptr);

    // --- unpool to level 1: hcat = x1_@W1o1 + s2@z2; x1o_ via MFMA ---
    gemm_ab32<<<dim3(4, 4), 256, 0, stream>>>(x2_, W1_out + 128 * 128, z2, 128, 128, 128, nullptr, 0, 0);
    gemm_ab32<<<dim3(4, 32), 256, 0, stream>>>(x1_, W1_out, hcat, 1024, 128, 128, nullptr, 0, 0);
    gemm_ab32<<<dim3(4, 32), 256, 0, stream>>>(s2, z2, hcat, 1024, 128, 128, nullptr, 0, 1);
    k_transpose_f2b<<<dim3(2, 16), 256, 0, stream>>>(hcat, HCATT, 1024, 128, nullptr);
    gemm_tn_bf16_part<<<dim3(8, 1, 8), 256, 0, stream>>>(AN1TB, HCATT, PP, 1024, 128, 1024);
    k_reduce_br<<<128, 256, 0, stream>>>(PP, x1o_, 1024 * 128, 128, 8, b1_out, 1);

    // --- unpool to level 0: p16 = x0_@W0out1 + s1o@(x1o_@W0out2) ---
    k_gemm_n16<<<64, 256, 0, stream>>>(x1o_, W0_out + 128 * 16, y16, 1024, 128, 0);
    k_gemm_n16<<<512, 256, 0, stream>>>(x0_, W0_out, p16, 8192, 128, 0);
    k_gemm_n16<<<512, 256, 0, stream>>>(s1o, y16, p16, 8192, 1024, 1);
    k_agg16_ls<<<512, 256, 0, stream>>>(p16, predo, cptr, colr, coln, dinv, b0_out);

    k_finalize<<<1, 64, 0, stream>>>(scal, losso);
}